// Round 1
// baseline (1819.927 us; speedup 1.0000x reference)
//
#include <hip/hip_runtime.h>

#define NN 40000
#define NE 640000
#define NG 64

// ---------------- scatter-add: agg[dst[e]] += feat[src[e]], row width D = 4*D4 ----------------
template<int D4>
__global__ void scatter_kernel(const float4* __restrict__ feat,
                               const int* __restrict__ src,
                               const int* __restrict__ dst,
                               float* __restrict__ agg, int nE) {
    int idx = blockIdx.x * blockDim.x + threadIdx.x;
    if (idx >= nE * D4) return;
    int e = idx / D4;
    int c = idx % D4;
    int s = src[e];
    int d = dst[e];
    float4 v = feat[(size_t)s * D4 + c];
    float* base = agg + (size_t)d * (D4 * 4) + c * 4;
    atomicAdd(base + 0, v.x);
    atomicAdd(base + 1, v.y);
    atomicAdd(base + 2, v.z);
    atomicAdd(base + 3, v.w);
}

// ---------------- layer 1 (aggregate-first): out = act(agg@Wrel + h@Wroot + b) ----------------
template<int K, int DOUT, bool RELU>
__global__ void conv_kernel(const float* __restrict__ agg,
                            const float* __restrict__ h,
                            const float* __restrict__ Wrel,
                            const float* __restrict__ Wroot,
                            const float* __restrict__ bias,
                            float* __restrict__ out, int n) {
    __shared__ float sWrel[K * DOUT];
    __shared__ float sWroot[K * DOUT];
    for (int i = threadIdx.x; i < K * DOUT; i += blockDim.x) {
        sWrel[i] = Wrel[i];
        sWroot[i] = Wroot[i];
    }
    __syncthreads();
    constexpr int NPB = 256 / DOUT;
    int node = blockIdx.x * NPB + threadIdx.x / DOUT;
    int j = threadIdx.x % DOUT;
    if (node >= n) return;
    const float* ar = agg + (size_t)node * K;
    const float* hr = h + (size_t)node * K;
    float acc = bias[j];
#pragma unroll
    for (int k = 0; k < K; ++k)
        acc += ar[k] * sWrel[k * DOUT + j] + hr[k] * sWroot[k * DOUT + j];
    out[(size_t)node * DOUT + j] = RELU ? fmaxf(acc, 0.f) : acc;
}

// ---------------- plain matmul: y = h @ W  (K x DOUT weights) ----------------
template<int K, int DOUT>
__global__ void mm_kernel(const float* __restrict__ h,
                          const float* __restrict__ W,
                          float* __restrict__ y, int n) {
    __shared__ float sW[K * DOUT];
    for (int i = threadIdx.x; i < K * DOUT; i += blockDim.x) sW[i] = W[i];
    __syncthreads();
    constexpr int NPB = 256 / DOUT;
    int node = blockIdx.x * NPB + threadIdx.x / DOUT;
    int j = threadIdx.x % DOUT;
    if (node >= n) return;
    const float* hr = h + (size_t)node * K;
    float acc = 0.f;
#pragma unroll
    for (int k = 0; k < K; ++k) acc += hr[k] * sW[k * DOUT + j];
    y[(size_t)node * DOUT + j] = acc;
}

// ---------------- transform-first epilogue: out = act(aggY + h@Wroot + b) ----------------
template<int K, int DOUT, bool RELU>
__global__ void epilogue_kernel(const float* __restrict__ aggy,
                                const float* __restrict__ h,
                                const float* __restrict__ Wroot,
                                const float* __restrict__ bias,
                                float* __restrict__ out, int n) {
    __shared__ float sW[K * DOUT];
    for (int i = threadIdx.x; i < K * DOUT; i += blockDim.x) sW[i] = Wroot[i];
    __syncthreads();
    constexpr int NPB = 256 / DOUT;
    int node = blockIdx.x * NPB + threadIdx.x / DOUT;
    int j = threadIdx.x % DOUT;
    if (node >= n) return;
    const float* hr = h + (size_t)node * K;
    float acc = aggy[(size_t)node * DOUT + j] + bias[j];
#pragma unroll
    for (int k = 0; k < K; ++k) acc += hr[k] * sW[k * DOUT + j];
    out[(size_t)node * DOUT + j] = RELU ? fmaxf(acc, 0.f) : acc;
}

// ---------------- mean-pool accumulation ----------------
__global__ void pool_kernel(const float* __restrict__ h,
                            const int* __restrict__ batch,
                            float* __restrict__ sums,
                            float* __restrict__ counts, int n) {
    int idx = blockIdx.x * blockDim.x + threadIdx.x;
    int node = idx >> 4;
    int f = idx & 15;
    if (node >= n) return;
    int g = batch[node];
    atomicAdd(&sums[g * 16 + f], h[idx]);
    if (f == 0) atomicAdd(&counts[g], 1.0f);
}

// ---------------- final FC ----------------
__global__ void fc_kernel(const float* __restrict__ sums,
                          const float* __restrict__ counts,
                          const float* __restrict__ Wfc,
                          const float* __restrict__ bfc,
                          float* __restrict__ out) {
    int g = threadIdx.x;
    if (g >= NG) return;
    float c = fmaxf(counts[g], 1.0f);
    float acc = bfc[0];
#pragma unroll
    for (int f = 0; f < 16; ++f) acc += (sums[g * 16 + f] / c) * Wfc[f];
    out[g] = acc;
}

extern "C" void kernel_launch(void* const* d_in, const int* in_sizes, int n_in,
                              void* d_out, int out_size, void* d_ws, size_t ws_size,
                              hipStream_t stream) {
    const float* x       = (const float*)d_in[0];
    const int*   ei      = (const int*)d_in[1];
    const int*   batch   = (const int*)d_in[2];
    const float* W1_rel  = (const float*)d_in[3];
    const float* b1      = (const float*)d_in[4];
    const float* W1_root = (const float*)d_in[5];
    const float* W2_rel  = (const float*)d_in[6];
    const float* b2      = (const float*)d_in[7];
    const float* W2_root = (const float*)d_in[8];
    const float* W3_rel  = (const float*)d_in[9];
    const float* b3      = (const float*)d_in[10];
    const float* W3_root = (const float*)d_in[11];
    const float* W4_rel  = (const float*)d_in[12];
    const float* b4      = (const float*)d_in[13];
    const float* W4_root = (const float*)d_in[14];
    const float* Wfc     = (const float*)d_in[15];
    const float* bfc     = (const float*)d_in[16];
    float* out = (float*)d_out;

    const int* src = ei;        // edge_index[0]
    const int* dst = ei + NE;   // edge_index[1]

    float* bufA   = (float*)d_ws;                 // N x 128
    float* bufB   = bufA + (size_t)NN * 128;      // N x 64
    float* bufC   = bufB + (size_t)NN * 64;       // N x 64 (agg scratch)
    float* sums   = bufC + (size_t)NN * 64;       // G x 16
    float* counts = sums + NG * 16;               // G

    // ---- Layer 1: aggregate-first (din=32 < dout=128) ----
    hipMemsetAsync(bufC, 0, (size_t)NN * 32 * 4, stream);
    scatter_kernel<8><<<NE * 8 / 256, 256, 0, stream>>>((const float4*)x, src, dst, bufC, NE);
    conv_kernel<32, 128, true><<<NN / 2, 256, 0, stream>>>(bufC, x, W1_rel, W1_root, b1, bufA, NN);

    // ---- Layer 2: transform-first (dout=64 < din=128) ----
    mm_kernel<128, 64><<<NN / 4, 256, 0, stream>>>(bufA, W2_rel, bufB, NN);
    hipMemsetAsync(bufC, 0, (size_t)NN * 64 * 4, stream);
    scatter_kernel<16><<<NE * 16 / 256, 256, 0, stream>>>((const float4*)bufB, src, dst, bufC, NE);
    epilogue_kernel<128, 64, true><<<NN / 4, 256, 0, stream>>>(bufC, bufA, W2_root, b2, bufB, NN);

    // ---- Layer 3: transform-first (64 -> 32) ----
    mm_kernel<64, 32><<<NN / 8, 256, 0, stream>>>(bufB, W3_rel, bufA, NN);
    hipMemsetAsync(bufC, 0, (size_t)NN * 32 * 4, stream);
    scatter_kernel<8><<<NE * 8 / 256, 256, 0, stream>>>((const float4*)bufA, src, dst, bufC, NE);
    epilogue_kernel<64, 32, true><<<NN / 8, 256, 0, stream>>>(bufC, bufB, W3_root, b3, bufA, NN);

    // ---- Layer 4: transform-first (32 -> 16), no ReLU ----
    mm_kernel<32, 16><<<NN / 16, 256, 0, stream>>>(bufA, W4_rel, bufB, NN);
    hipMemsetAsync(bufC, 0, (size_t)NN * 16 * 4, stream);
    scatter_kernel<4><<<NE * 4 / 256, 256, 0, stream>>>((const float4*)bufB, src, dst, bufC, NE);
    epilogue_kernel<32, 16, false><<<NN / 16, 256, 0, stream>>>(bufC, bufA, W4_root, b4, bufB, NN);

    // ---- Global mean pool + FC ----
    hipMemsetAsync(sums, 0, (size_t)(NG * 16 + NG) * 4, stream);
    pool_kernel<<<NN * 16 / 256, 256, 0, stream>>>(bufB, batch, sums, counts, NN);
    fc_kernel<<<1, 64, 0, stream>>>(sums, counts, Wfc, bfc, out);
}

// Round 2
// 720.996 us; speedup vs baseline: 2.5242x; 2.5242x over previous
//
#include <hip/hip_runtime.h>

#define NN 40000
#define NE 640000
#define NG 64

// ================= CSR build =================
__global__ void hist_kernel(const int* __restrict__ dst, int* __restrict__ deg) {
    int e = blockIdx.x * blockDim.x + threadIdx.x;
    if (e < NE) atomicAdd(&deg[dst[e]], 1);
}

// single-block exclusive scan over deg[NN] -> rowptr[NN+1], cursor[NN]
__global__ void scan_kernel(const int* __restrict__ deg,
                            int* __restrict__ rowptr,
                            int* __restrict__ cursor) {
    __shared__ int wsum[16];
    __shared__ int wpre[16];
    __shared__ int s_carry;
    __shared__ int s_total;
    int lane = threadIdx.x & 63;
    int wid = threadIdx.x >> 6;
    if (threadIdx.x == 0) s_carry = 0;
    __syncthreads();
    for (int base = 0; base < NN; base += 1024) {
        int i = base + threadIdx.x;
        int v = (i < NN) ? deg[i] : 0;
        int incl = v;
#pragma unroll
        for (int off = 1; off < 64; off <<= 1) {
            int t = __shfl_up(incl, off, 64);
            if (lane >= off) incl += t;
        }
        if (lane == 63) wsum[wid] = incl;
        __syncthreads();
        if (wid == 0 && lane < 16) {
            int wv = wsum[lane];
            int winc = wv;
#pragma unroll
            for (int off = 1; off < 16; off <<= 1) {
                int t = __shfl_up(winc, off, 64);
                if (lane >= off) winc += t;
            }
            wpre[lane] = winc - wv;
            if (lane == 15) s_total = winc;
        }
        __syncthreads();
        int carry = s_carry;
        int excl = carry + wpre[wid] + (incl - v);
        if (i < NN) { rowptr[i] = excl; cursor[i] = excl; }
        __syncthreads();
        if (threadIdx.x == 0) s_carry = carry + s_total;
        __syncthreads();
    }
    if (threadIdx.x == 0) rowptr[NN] = s_carry;
}

__global__ void fill_kernel(const int* __restrict__ src, const int* __restrict__ dst,
                            int* __restrict__ cursor, int* __restrict__ col) {
    int e = blockIdx.x * blockDim.x + threadIdx.x;
    if (e < NE) {
        int pos = atomicAdd(&cursor[dst[e]], 1);
        col[pos] = src[e];
    }
}

// ================= pure gather aggregation (layer 1, D = 4*D4) =================
template<int D4>
__global__ void gather_kernel(const float4* __restrict__ feat,
                              const int* __restrict__ rowptr,
                              const int* __restrict__ col,
                              float4* __restrict__ agg, int n) {
    int idx = blockIdx.x * blockDim.x + threadIdx.x;
    int node = idx / D4, c = idx % D4;
    if (node >= n) return;
    int beg = rowptr[node], end = rowptr[node + 1];
    float4 a = {0.f, 0.f, 0.f, 0.f};
    for (int e = beg; e < end; ++e) {
        float4 v = feat[(size_t)col[e] * D4 + c];
        a.x += v.x; a.y += v.y; a.z += v.z; a.w += v.w;
    }
    agg[(size_t)node * D4 + c] = a;
}

// ============ layer 1 conv: out = relu(agg@Wrel + x@Wroot + b), 32 -> 128 ============
template<int K, int DOUT, bool RELU>
__global__ void conv_kernel(const float* __restrict__ agg,
                            const float* __restrict__ h,
                            const float* __restrict__ Wrel,
                            const float* __restrict__ Wroot,
                            const float* __restrict__ bias,
                            float* __restrict__ out, int n) {
    __shared__ float sWrel[K * DOUT];
    __shared__ float sWroot[K * DOUT];
    for (int i = threadIdx.x; i < K * DOUT; i += blockDim.x) {
        sWrel[i] = Wrel[i];
        sWroot[i] = Wroot[i];
    }
    __syncthreads();
    constexpr int NPB = 256 / DOUT;
    int node = blockIdx.x * NPB + threadIdx.x / DOUT;
    int j = threadIdx.x % DOUT;
    if (node >= n) return;
    const float* ar = agg + (size_t)node * K;
    const float* hr = h + (size_t)node * K;
    float acc = bias[j];
#pragma unroll
    for (int k = 0; k < K; ++k)
        acc += ar[k] * sWrel[k * DOUT + j] + hr[k] * sWroot[k * DOUT + j];
    out[(size_t)node * DOUT + j] = RELU ? fmaxf(acc, 0.f) : acc;
}

// ================= plain matmul: y = h @ W =================
template<int K, int DOUT>
__global__ void mm_kernel(const float* __restrict__ h,
                          const float* __restrict__ W,
                          float* __restrict__ y, int n) {
    __shared__ float sW[K * DOUT];
    for (int i = threadIdx.x; i < K * DOUT; i += blockDim.x) sW[i] = W[i];
    __syncthreads();
    constexpr int NPB = 256 / DOUT;
    int node = blockIdx.x * NPB + threadIdx.x / DOUT;
    int j = threadIdx.x % DOUT;
    if (node >= n) return;
    const float* hr = h + (size_t)node * K;
    float acc = 0.f;
#pragma unroll
    for (int k = 0; k < K; ++k) acc += hr[k] * sW[k * DOUT + j];
    y[(size_t)node * DOUT + j] = acc;
}

// ===== fused gather + root epilogue: out = act(sum_{j->i} y_j + h_i@Wroot + b) =====
template<int K, int D4, bool RELU>   // DOUT = 4*D4
__global__ void gather_epi_kernel(const float4* __restrict__ y,
                                  const float* __restrict__ h,
                                  const int* __restrict__ rowptr,
                                  const int* __restrict__ col,
                                  const float4* __restrict__ Wroot,  // K x D4 float4s
                                  const float4* __restrict__ bias,   // D4 float4s
                                  float4* __restrict__ out, int n) {
    __shared__ float4 sW[K * D4];
    for (int i = threadIdx.x; i < K * D4; i += blockDim.x) sW[i] = Wroot[i];
    __syncthreads();
    int idx = blockIdx.x * blockDim.x + threadIdx.x;
    int node = idx / D4, c = idx % D4;
    if (node >= n) return;
    float4 a = bias[c];
    int beg = rowptr[node], end = rowptr[node + 1];
    for (int e = beg; e < end; ++e) {
        float4 v = y[(size_t)col[e] * D4 + c];
        a.x += v.x; a.y += v.y; a.z += v.z; a.w += v.w;
    }
    const float* hr = h + (size_t)node * K;
#pragma unroll
    for (int k = 0; k < K; ++k) {
        float hv = hr[k];
        float4 w = sW[k * D4 + c];
        a.x += hv * w.x; a.y += hv * w.y; a.z += hv * w.z; a.w += hv * w.w;
    }
    float4 r;
    if (RELU) {
        r.x = fmaxf(a.x, 0.f); r.y = fmaxf(a.y, 0.f);
        r.z = fmaxf(a.z, 0.f); r.w = fmaxf(a.w, 0.f);
    } else r = a;
    out[(size_t)node * D4 + c] = r;
}

// ================= mean-pool accumulation =================
__global__ void pool_kernel(const float* __restrict__ h,
                            const int* __restrict__ batch,
                            float* __restrict__ sums,
                            float* __restrict__ counts, int n) {
    int idx = blockIdx.x * blockDim.x + threadIdx.x;
    int node = idx >> 4;
    int f = idx & 15;
    if (node >= n) return;
    int g = batch[node];
    atomicAdd(&sums[g * 16 + f], h[idx]);
    if (f == 0) atomicAdd(&counts[g], 1.0f);
}

// ================= final FC =================
__global__ void fc_kernel(const float* __restrict__ sums,
                          const float* __restrict__ counts,
                          const float* __restrict__ Wfc,
                          const float* __restrict__ bfc,
                          float* __restrict__ out) {
    int g = threadIdx.x;
    if (g >= NG) return;
    float c = fmaxf(counts[g], 1.0f);
    float acc = bfc[0];
#pragma unroll
    for (int f = 0; f < 16; ++f) acc += (sums[g * 16 + f] / c) * Wfc[f];
    out[g] = acc;
}

extern "C" void kernel_launch(void* const* d_in, const int* in_sizes, int n_in,
                              void* d_out, int out_size, void* d_ws, size_t ws_size,
                              hipStream_t stream) {
    const float* x       = (const float*)d_in[0];
    const int*   ei      = (const int*)d_in[1];
    const int*   batch   = (const int*)d_in[2];
    const float* W1_rel  = (const float*)d_in[3];
    const float* b1      = (const float*)d_in[4];
    const float* W1_root = (const float*)d_in[5];
    const float* W2_rel  = (const float*)d_in[6];
    const float* b2      = (const float*)d_in[7];
    const float* W2_root = (const float*)d_in[8];
    const float* W3_rel  = (const float*)d_in[9];
    const float* b3      = (const float*)d_in[10];
    const float* W3_root = (const float*)d_in[11];
    const float* W4_rel  = (const float*)d_in[12];
    const float* b4      = (const float*)d_in[13];
    const float* W4_root = (const float*)d_in[14];
    const float* Wfc     = (const float*)d_in[15];
    const float* bfc     = (const float*)d_in[16];
    float* out = (float*)d_out;

    const int* src = ei;        // edge_index[0]
    const int* dst = ei + NE;   // edge_index[1]

    // workspace layout
    float* bufA   = (float*)d_ws;                  // N x 128
    float* bufB   = bufA + (size_t)NN * 128;       // N x 64
    float* bufC   = bufB + (size_t)NN * 64;        // N x 64
    int*   deg    = (int*)(bufC + (size_t)NN * 64);// N
    int*   rowptr = deg + NN;                      // N+1
    int*   cursor = rowptr + NN + 1;               // N
    int*   col    = cursor + NN;                   // E
    float* sums   = (float*)(col + NE);            // G x 16
    float* counts = sums + NG * 16;                // G

    // ---- build CSR (dst-sorted reverse adjacency), once per launch ----
    hipMemsetAsync(deg, 0, NN * sizeof(int), stream);
    hist_kernel<<<(NE + 255) / 256, 256, 0, stream>>>(dst, deg);
    scan_kernel<<<1, 1024, 0, stream>>>(deg, rowptr, cursor);
    fill_kernel<<<(NE + 255) / 256, 256, 0, stream>>>(src, dst, cursor, col);

    // ---- Layer 1: aggregate-first (din=32 < dout=128) ----
    gather_kernel<8><<<(NN * 8 + 255) / 256, 256, 0, stream>>>(
        (const float4*)x, rowptr, col, (float4*)bufB, NN);
    conv_kernel<32, 128, true><<<NN / 2, 256, 0, stream>>>(bufB, x, W1_rel, W1_root, b1, bufA, NN);

    // ---- Layer 2: transform-first (128 -> 64) ----
    mm_kernel<128, 64><<<NN / 4, 256, 0, stream>>>(bufA, W2_rel, bufB, NN);
    gather_epi_kernel<128, 16, true><<<(NN * 16 + 255) / 256, 256, 0, stream>>>(
        (const float4*)bufB, bufA, rowptr, col,
        (const float4*)W2_root, (const float4*)b2, (float4*)bufC, NN);

    // ---- Layer 3: transform-first (64 -> 32) ----
    mm_kernel<64, 32><<<NN / 8, 256, 0, stream>>>(bufC, W3_rel, bufB, NN);
    gather_epi_kernel<64, 8, true><<<(NN * 8 + 255) / 256, 256, 0, stream>>>(
        (const float4*)bufB, bufC, rowptr, col,
        (const float4*)W3_root, (const float4*)b3, (float4*)bufA, NN);

    // ---- Layer 4: transform-first (32 -> 16), no ReLU ----
    mm_kernel<32, 16><<<NN / 16, 256, 0, stream>>>(bufA, W4_rel, bufB, NN);
    gather_epi_kernel<32, 4, false><<<(NN * 4 + 255) / 256, 256, 0, stream>>>(
        (const float4*)bufB, bufA, rowptr, col,
        (const float4*)W4_root, (const float4*)b4, (float4*)bufC, NN);

    // ---- Global mean pool + FC ----
    hipMemsetAsync(sums, 0, (size_t)(NG * 16 + NG) * sizeof(float), stream);
    pool_kernel<<<NN * 16 / 256, 256, 0, stream>>>(bufC, batch, sums, counts, NN);
    fc_kernel<<<1, 64, 0, stream>>>(sums, counts, Wfc, bfc, out);
}

// Round 3
// 462.469 us; speedup vs baseline: 3.9352x; 1.5590x over previous
//
#include <hip/hip_runtime.h>

#define NN 40000
#define NE 640000
#define NG 64

// ================= CSR build =================
__global__ void hist_kernel(const int* __restrict__ dst, int* __restrict__ deg) {
    int e = blockIdx.x * blockDim.x + threadIdx.x;
    if (e < NE) atomicAdd(&deg[dst[e]], 1);
}

// single-block exclusive scan over deg[NN] -> rowptr[NN+1], cursor[NN]
__global__ void scan_kernel(const int* __restrict__ deg,
                            int* __restrict__ rowptr,
                            int* __restrict__ cursor) {
    __shared__ int wsum[16];
    __shared__ int wpre[16];
    __shared__ int s_carry;
    __shared__ int s_total;
    int lane = threadIdx.x & 63;
    int wid = threadIdx.x >> 6;
    if (threadIdx.x == 0) s_carry = 0;
    __syncthreads();
    for (int base = 0; base < NN; base += 1024) {
        int i = base + threadIdx.x;
        int v = (i < NN) ? deg[i] : 0;
        int incl = v;
#pragma unroll
        for (int off = 1; off < 64; off <<= 1) {
            int t = __shfl_up(incl, off, 64);
            if (lane >= off) incl += t;
        }
        if (lane == 63) wsum[wid] = incl;
        __syncthreads();
        if (wid == 0 && lane < 16) {
            int wv = wsum[lane];
            int winc = wv;
#pragma unroll
            for (int off = 1; off < 16; off <<= 1) {
                int t = __shfl_up(winc, off, 64);
                if (lane >= off) winc += t;
            }
            wpre[lane] = winc - wv;
            if (lane == 15) s_total = winc;
        }
        __syncthreads();
        int carry = s_carry;
        int excl = carry + wpre[wid] + (incl - v);
        if (i < NN) { rowptr[i] = excl; cursor[i] = excl; }
        __syncthreads();
        if (threadIdx.x == 0) s_carry = carry + s_total;
        __syncthreads();
    }
    if (threadIdx.x == 0) rowptr[NN] = s_carry;
}

__global__ void fill_kernel(const int* __restrict__ src, const int* __restrict__ dst,
                            int* __restrict__ cursor, int* __restrict__ col) {
    int e = blockIdx.x * blockDim.x + threadIdx.x;
    if (e < NE) {
        int pos = atomicAdd(&cursor[dst[e]], 1);
        col[pos] = src[e];
    }
}

// ================= pure gather aggregation (layer 1, D = 4*D4) =================
template<int D4>
__global__ void gather_kernel(const float4* __restrict__ feat,
                              const int* __restrict__ rowptr,
                              const int* __restrict__ col,
                              float4* __restrict__ agg, int n) {
    int idx = blockIdx.x * blockDim.x + threadIdx.x;
    int node = idx / D4, c = idx % D4;
    if (node >= n) return;
    int beg = rowptr[node], end = rowptr[node + 1];
    float4 a = {0.f, 0.f, 0.f, 0.f};
    for (int e = beg; e < end; ++e) {
        float4 v = feat[(size_t)col[e] * D4 + c];
        a.x += v.x; a.y += v.y; a.z += v.z; a.w += v.w;
    }
    agg[(size_t)node * D4 + c] = a;
}

// ============ layer 1 conv: out = relu(agg@Wrel + x@Wroot + b), 32 -> 128 ============
template<int K, int DOUT, bool RELU>
__global__ void conv_kernel(const float* __restrict__ agg,
                            const float* __restrict__ h,
                            const float* __restrict__ Wrel,
                            const float* __restrict__ Wroot,
                            const float* __restrict__ bias,
                            float* __restrict__ out, int n) {
    __shared__ float sWrel[K * DOUT];
    __shared__ float sWroot[K * DOUT];
    for (int i = threadIdx.x; i < K * DOUT; i += blockDim.x) {
        sWrel[i] = Wrel[i];
        sWroot[i] = Wroot[i];
    }
    __syncthreads();
    constexpr int NPB = 256 / DOUT;
    int node = blockIdx.x * NPB + threadIdx.x / DOUT;
    int j = threadIdx.x % DOUT;
    if (node >= n) return;
    const float* ar = agg + (size_t)node * K;
    const float* hr = h + (size_t)node * K;
    float acc = bias[j];
#pragma unroll
    for (int k = 0; k < K; ++k)
        acc += ar[k] * sWrel[k * DOUT + j] + hr[k] * sWroot[k * DOUT + j];
    out[(size_t)node * DOUT + j] = RELU ? fmaxf(acc, 0.f) : acc;
}

// ================= plain matmul: y = h @ W =================
template<int K, int DOUT>
__global__ void mm_kernel(const float* __restrict__ h,
                          const float* __restrict__ W,
                          float* __restrict__ y, int n) {
    __shared__ float sW[K * DOUT];
    for (int i = threadIdx.x; i < K * DOUT; i += blockDim.x) sW[i] = W[i];
    __syncthreads();
    constexpr int NPB = 256 / DOUT;
    int node = blockIdx.x * NPB + threadIdx.x / DOUT;
    int j = threadIdx.x % DOUT;
    if (node >= n) return;
    const float* hr = h + (size_t)node * K;
    float acc = 0.f;
#pragma unroll
    for (int k = 0; k < K; ++k) acc += hr[k] * sW[k * DOUT + j];
    y[(size_t)node * DOUT + j] = acc;
}

// ===== fused gather + root epilogue: out = act(sum_{j->i} y_j + h_i@Wroot + b) =====
template<int K, int D4, bool RELU>   // DOUT = 4*D4
__global__ void gather_epi_kernel(const float4* __restrict__ y,
                                  const float* __restrict__ h,
                                  const int* __restrict__ rowptr,
                                  const int* __restrict__ col,
                                  const float4* __restrict__ Wroot,  // K x D4 float4s
                                  const float4* __restrict__ bias,   // D4 float4s
                                  float4* __restrict__ out, int n) {
    __shared__ float4 sW[K * D4];
    for (int i = threadIdx.x; i < K * D4; i += blockDim.x) sW[i] = Wroot[i];
    __syncthreads();
    int idx = blockIdx.x * blockDim.x + threadIdx.x;
    int node = idx / D4, c = idx % D4;
    if (node >= n) return;
    float4 a = bias[c];
    int beg = rowptr[node], end = rowptr[node + 1];
    for (int e = beg; e < end; ++e) {
        float4 v = y[(size_t)col[e] * D4 + c];
        a.x += v.x; a.y += v.y; a.z += v.z; a.w += v.w;
    }
    const float* hr = h + (size_t)node * K;
#pragma unroll
    for (int k = 0; k < K; ++k) {
        float hv = hr[k];
        float4 w = sW[k * D4 + c];
        a.x += hv * w.x; a.y += hv * w.y; a.z += hv * w.z; a.w += hv * w.w;
    }
    float4 r;
    if (RELU) {
        r.x = fmaxf(a.x, 0.f); r.y = fmaxf(a.y, 0.f);
        r.z = fmaxf(a.z, 0.f); r.w = fmaxf(a.w, 0.f);
    } else r = a;
    out[(size_t)node * D4 + c] = r;
}

// ======== mean-pool: run-based segmented reduction (batch is SORTED) ========
// thread -> feature lane f = tid&15, contiguous node strip; flush one atomic
// per (graph-run x feat) instead of per element.
#define POOL_BLOCKS 40
__global__ void pool_kernel(const float* __restrict__ h,
                            const int* __restrict__ batch,
                            float* __restrict__ sums,
                            float* __restrict__ counts) {
    const int GROUPS = POOL_BLOCKS * 256 / 16;           // 640 node strips
    const int PER = (NN + GROUPS - 1) / GROUPS;          // 63
    int tid = blockIdx.x * blockDim.x + threadIdx.x;
    int f = tid & 15;
    int grp = tid >> 4;
    int n0 = grp * PER;
    int n1 = n0 + PER < NN ? n0 + PER : NN;
    if (n0 >= NN) return;
    int gcur = batch[n0];
    float acc = 0.f, cnt = 0.f;
    for (int n = n0; n < n1; ++n) {
        int g = batch[n];
        if (g != gcur) {
            atomicAdd(&sums[gcur * 16 + f], acc);
            if (f == 0) atomicAdd(&counts[gcur], cnt);
            acc = 0.f; cnt = 0.f; gcur = g;
        }
        acc += h[(size_t)n * 16 + f];
        cnt += 1.f;
    }
    atomicAdd(&sums[gcur * 16 + f], acc);
    if (f == 0) atomicAdd(&counts[gcur], cnt);
}

// ================= final FC =================
__global__ void fc_kernel(const float* __restrict__ sums,
                          const float* __restrict__ counts,
                          const float* __restrict__ Wfc,
                          const float* __restrict__ bfc,
                          float* __restrict__ out) {
    int g = threadIdx.x;
    if (g >= NG) return;
    float c = fmaxf(counts[g], 1.0f);
    float acc = bfc[0];
#pragma unroll
    for (int f = 0; f < 16; ++f) acc += (sums[g * 16 + f] / c) * Wfc[f];
    out[g] = acc;
}

extern "C" void kernel_launch(void* const* d_in, const int* in_sizes, int n_in,
                              void* d_out, int out_size, void* d_ws, size_t ws_size,
                              hipStream_t stream) {
    const float* x       = (const float*)d_in[0];
    const int*   ei      = (const int*)d_in[1];
    const int*   batch   = (const int*)d_in[2];
    const float* W1_rel  = (const float*)d_in[3];
    const float* b1      = (const float*)d_in[4];
    const float* W1_root = (const float*)d_in[5];
    const float* W2_rel  = (const float*)d_in[6];
    const float* b2      = (const float*)d_in[7];
    const float* W2_root = (const float*)d_in[8];
    const float* W3_rel  = (const float*)d_in[9];
    const float* b3      = (const float*)d_in[10];
    const float* W3_root = (const float*)d_in[11];
    const float* W4_rel  = (const float*)d_in[12];
    const float* b4      = (const float*)d_in[13];
    const float* W4_root = (const float*)d_in[14];
    const float* Wfc     = (const float*)d_in[15];
    const float* bfc     = (const float*)d_in[16];
    float* out = (float*)d_out;

    const int* src = ei;        // edge_index[0]
    const int* dst = ei + NE;   // edge_index[1]

    // workspace layout
    float* bufA   = (float*)d_ws;                  // N x 128
    float* bufB   = bufA + (size_t)NN * 128;       // N x 64
    float* bufC   = bufB + (size_t)NN * 64;        // N x 64
    int*   deg    = (int*)(bufC + (size_t)NN * 64);// N
    int*   rowptr = deg + NN;                      // N+1
    int*   cursor = rowptr + NN + 1;               // N
    int*   col    = cursor + NN;                   // E
    float* sums   = (float*)(col + NE);            // G x 16
    float* counts = sums + NG * 16;                // G

    // ---- build CSR (dst-sorted reverse adjacency), once per launch ----
    hipMemsetAsync(deg, 0, NN * sizeof(int), stream);
    hist_kernel<<<(NE + 255) / 256, 256, 0, stream>>>(dst, deg);
    scan_kernel<<<1, 1024, 0, stream>>>(deg, rowptr, cursor);
    fill_kernel<<<(NE + 255) / 256, 256, 0, stream>>>(src, dst, cursor, col);

    // ---- Layer 1: aggregate-first (din=32 < dout=128) ----
    gather_kernel<8><<<(NN * 8 + 255) / 256, 256, 0, stream>>>(
        (const float4*)x, rowptr, col, (float4*)bufB, NN);
    conv_kernel<32, 128, true><<<NN / 2, 256, 0, stream>>>(bufB, x, W1_rel, W1_root, b1, bufA, NN);

    // ---- Layer 2: transform-first (128 -> 64) ----
    mm_kernel<128, 64><<<NN / 4, 256, 0, stream>>>(bufA, W2_rel, bufB, NN);
    gather_epi_kernel<128, 16, true><<<(NN * 16 + 255) / 256, 256, 0, stream>>>(
        (const float4*)bufB, bufA, rowptr, col,
        (const float4*)W2_root, (const float4*)b2, (float4*)bufC, NN);

    // ---- Layer 3: transform-first (64 -> 32) ----
    mm_kernel<64, 32><<<NN / 8, 256, 0, stream>>>(bufC, W3_rel, bufB, NN);
    gather_epi_kernel<64, 8, true><<<(NN * 8 + 255) / 256, 256, 0, stream>>>(
        (const float4*)bufB, bufC, rowptr, col,
        (const float4*)W3_root, (const float4*)b3, (float4*)bufA, NN);

    // ---- Layer 4: transform-first (32 -> 16), no ReLU ----
    mm_kernel<32, 16><<<NN / 16, 256, 0, stream>>>(bufA, W4_rel, bufB, NN);
    gather_epi_kernel<32, 4, false><<<(NN * 4 + 255) / 256, 256, 0, stream>>>(
        (const float4*)bufB, bufA, rowptr, col,
        (const float4*)W4_root, (const float4*)b4, (float4*)bufC, NN);

    // ---- Global mean pool + FC ----
    hipMemsetAsync(sums, 0, (size_t)(NG * 16 + NG) * sizeof(float), stream);
    pool_kernel<<<POOL_BLOCKS, 256, 0, stream>>>(bufC, batch, sums, counts);
    fc_kernel<<<1, 64, 0, stream>>>(sums, counts, Wfc, bfc, out);
}

// Round 4
// 416.365 us; speedup vs baseline: 4.3710x; 1.1107x over previous
//
#include <hip/hip_runtime.h>

#define NN 40000
#define NE 640000
#define NG 64

__device__ __forceinline__ float fcomp(const float4& v, int t) {
    return t == 0 ? v.x : t == 1 ? v.y : t == 2 ? v.z : v.w;
}

// ================= CSR build =================
__global__ void hist_kernel(const int* __restrict__ dst, int* __restrict__ deg) {
    int e = blockIdx.x * blockDim.x + threadIdx.x;
    if (e < NE) atomicAdd(&deg[dst[e]], 1);
}

// single-block exclusive scan over deg[NN] -> rowptr[NN+1], cursor[NN]
__global__ void scan_kernel(const int* __restrict__ deg,
                            int* __restrict__ rowptr,
                            int* __restrict__ cursor) {
    __shared__ int wsum[16];
    __shared__ int wpre[16];
    __shared__ int s_carry;
    __shared__ int s_total;
    int lane = threadIdx.x & 63;
    int wid = threadIdx.x >> 6;
    if (threadIdx.x == 0) s_carry = 0;
    __syncthreads();
    for (int base = 0; base < NN; base += 1024) {
        int i = base + threadIdx.x;
        int v = (i < NN) ? deg[i] : 0;
        int incl = v;
#pragma unroll
        for (int off = 1; off < 64; off <<= 1) {
            int t = __shfl_up(incl, off, 64);
            if (lane >= off) incl += t;
        }
        if (lane == 63) wsum[wid] = incl;
        __syncthreads();
        if (wid == 0 && lane < 16) {
            int wv = wsum[lane];
            int winc = wv;
#pragma unroll
            for (int off = 1; off < 16; off <<= 1) {
                int t = __shfl_up(winc, off, 64);
                if (lane >= off) winc += t;
            }
            wpre[lane] = winc - wv;
            if (lane == 15) s_total = winc;
        }
        __syncthreads();
        int carry = s_carry;
        int excl = carry + wpre[wid] + (incl - v);
        if (i < NN) { rowptr[i] = excl; cursor[i] = excl; }
        __syncthreads();
        if (threadIdx.x == 0) s_carry = carry + s_total;
        __syncthreads();
    }
    if (threadIdx.x == 0) rowptr[NN] = s_carry;
}

__global__ void fill_kernel(const int* __restrict__ src, const int* __restrict__ dst,
                            int* __restrict__ cursor, int* __restrict__ col) {
    int e = blockIdx.x * blockDim.x + threadIdx.x;
    if (e < NE) {
        int pos = atomicAdd(&cursor[dst[e]], 1);
        col[pos] = src[e];
    }
}

// ===== pure gather: out = act(z + sum_{j->i} y_j), D = 4*D4, 4-way unrolled =====
template<int D4, bool RELU, bool HAS_Z>
__global__ __launch_bounds__(256) void gatherz_kernel(
        const float4* __restrict__ y,
        const float4* __restrict__ z,
        const int* __restrict__ rowptr,
        const int* __restrict__ col,
        float4* __restrict__ out, int n) {
    int idx = blockIdx.x * blockDim.x + threadIdx.x;
    int node = idx / D4, c = idx % D4;
    if (node >= n) return;
    int beg = rowptr[node], end = rowptr[node + 1];
    float4 a;
    if (HAS_Z) a = z[(size_t)node * D4 + c];
    else { a.x = 0.f; a.y = 0.f; a.z = 0.f; a.w = 0.f; }
    int e = beg;
    for (; e + 4 <= end; e += 4) {
        int c0 = col[e], c1 = col[e + 1], c2 = col[e + 2], c3 = col[e + 3];
        float4 v0 = y[(size_t)c0 * D4 + c];
        float4 v1 = y[(size_t)c1 * D4 + c];
        float4 v2 = y[(size_t)c2 * D4 + c];
        float4 v3 = y[(size_t)c3 * D4 + c];
        a.x += (v0.x + v1.x) + (v2.x + v3.x);
        a.y += (v0.y + v1.y) + (v2.y + v3.y);
        a.z += (v0.z + v1.z) + (v2.z + v3.z);
        a.w += (v0.w + v1.w) + (v2.w + v3.w);
    }
    for (; e < end; ++e) {
        float4 v = y[(size_t)col[e] * D4 + c];
        a.x += v.x; a.y += v.y; a.z += v.z; a.w += v.w;
    }
    if (RELU) {
        a.x = fmaxf(a.x, 0.f); a.y = fmaxf(a.y, 0.f);
        a.z = fmaxf(a.z, 0.f); a.w = fmaxf(a.w, 0.f);
    }
    out[(size_t)node * D4 + c] = a;
}

// ====== layer-1 conv, register-blocked: out = relu(agg@Wrel + x@Wroot + b) ======
// thread = 4 nodes x 4 outputs; weights in LDS; float4 everywhere.
template<int K, int DOUT>
__global__ __launch_bounds__(256) void conv1_kernel(
        const float4* __restrict__ agg,   // N x K/4
        const float4* __restrict__ x,     // N x K/4
        const float4* __restrict__ Wrel,  // K x DOUT/4
        const float4* __restrict__ Wroot, // K x DOUT/4
        const float4* __restrict__ bias,  // DOUT/4
        float4* __restrict__ out, int n) {
    constexpr int JL = DOUT / 4, MG = 256 / JL, NPB = MG * 4;
    __shared__ float4 sR[K * JL];
    __shared__ float4 sT[K * JL];
    for (int i = threadIdx.x; i < K * JL; i += 256) { sR[i] = Wrel[i]; sT[i] = Wroot[i]; }
    __syncthreads();
    int jl = threadIdx.x % JL;
    int mg = threadIdx.x / JL;
    int node0 = blockIdx.x * NPB + mg * 4;
    int nm[4]; bool ok[4];
#pragma unroll
    for (int m = 0; m < 4; ++m) {
        int nd = node0 + m; ok[m] = nd < n; nm[m] = ok[m] ? nd : n - 1;
    }
    float4 bb = bias[jl];
    float4 acc[4];
#pragma unroll
    for (int m = 0; m < 4; ++m) acc[m] = bb;
    for (int kc = 0; kc < K / 4; ++kc) {
        float4 a4[4], x4[4];
#pragma unroll
        for (int m = 0; m < 4; ++m) {
            a4[m] = agg[(size_t)nm[m] * (K / 4) + kc];
            x4[m] = x[(size_t)nm[m] * (K / 4) + kc];
        }
#pragma unroll
        for (int t = 0; t < 4; ++t) {
            float4 wr = sR[(kc * 4 + t) * JL + jl];
            float4 wt = sT[(kc * 4 + t) * JL + jl];
#pragma unroll
            for (int m = 0; m < 4; ++m) {
                float av = fcomp(a4[m], t), xv = fcomp(x4[m], t);
                acc[m].x += av * wr.x + xv * wt.x;
                acc[m].y += av * wr.y + xv * wt.y;
                acc[m].z += av * wr.z + xv * wt.z;
                acc[m].w += av * wr.w + xv * wt.w;
            }
        }
    }
#pragma unroll
    for (int m = 0; m < 4; ++m) {
        if (!ok[m]) continue;
        float4 r;
        r.x = fmaxf(acc[m].x, 0.f); r.y = fmaxf(acc[m].y, 0.f);
        r.z = fmaxf(acc[m].z, 0.f); r.w = fmaxf(acc[m].w, 0.f);
        out[(size_t)nm[m] * JL + jl] = r;
    }
}

// ====== fused transform: y = h@Wrel, z = h@Wroot + b, register-blocked ======
// thread = 4 nodes x 4 outputs; k-slab (32) staged weights in LDS.
template<int K, int DOUT>
__global__ __launch_bounds__(256) void mmyz_kernel(
        const float4* __restrict__ h,     // N x K/4
        const float4* __restrict__ Wrel,  // K x DOUT/4
        const float4* __restrict__ Wroot, // K x DOUT/4
        const float4* __restrict__ bias,  // DOUT/4
        float4* __restrict__ y,
        float4* __restrict__ z, int n) {
    constexpr int JL = DOUT / 4, MG = 256 / JL, NPB = MG * 4;
    constexpr int SLAB = 32, NS = K / SLAB;
    __shared__ float4 sR[SLAB * JL];
    __shared__ float4 sT[SLAB * JL];
    int jl = threadIdx.x % JL;
    int mg = threadIdx.x / JL;
    int node0 = blockIdx.x * NPB + mg * 4;
    int nm[4]; bool ok[4];
#pragma unroll
    for (int m = 0; m < 4; ++m) {
        int nd = node0 + m; ok[m] = nd < n; nm[m] = ok[m] ? nd : n - 1;
    }
    float4 bb = bias[jl];
    float4 ay[4], az[4];
#pragma unroll
    for (int m = 0; m < 4; ++m) {
        ay[m].x = 0.f; ay[m].y = 0.f; ay[m].z = 0.f; ay[m].w = 0.f;
        az[m] = bb;
    }
    for (int s = 0; s < NS; ++s) {
        __syncthreads();
        for (int i = threadIdx.x; i < SLAB * JL; i += 256) {
            sR[i] = Wrel[s * SLAB * JL + i];
            sT[i] = Wroot[s * SLAB * JL + i];
        }
        __syncthreads();
        for (int kc = 0; kc < SLAB / 4; ++kc) {
            float4 h4[4];
#pragma unroll
            for (int m = 0; m < 4; ++m)
                h4[m] = h[(size_t)nm[m] * (K / 4) + s * (SLAB / 4) + kc];
#pragma unroll
            for (int t = 0; t < 4; ++t) {
                float4 wr = sR[(kc * 4 + t) * JL + jl];
                float4 wt = sT[(kc * 4 + t) * JL + jl];
#pragma unroll
                for (int m = 0; m < 4; ++m) {
                    float hv = fcomp(h4[m], t);
                    ay[m].x += hv * wr.x; ay[m].y += hv * wr.y;
                    ay[m].z += hv * wr.z; ay[m].w += hv * wr.w;
                    az[m].x += hv * wt.x; az[m].y += hv * wt.y;
                    az[m].z += hv * wt.z; az[m].w += hv * wt.w;
                }
            }
        }
    }
#pragma unroll
    for (int m = 0; m < 4; ++m) {
        if (!ok[m]) continue;
        y[(size_t)nm[m] * JL + jl] = ay[m];
        z[(size_t)nm[m] * JL + jl] = az[m];
    }
}

// ======== mean-pool: run-based segmented reduction (batch is SORTED) ========
#define POOL_BLOCKS 40
__global__ void pool_kernel(const float* __restrict__ h,
                            const int* __restrict__ batch,
                            float* __restrict__ sums,
                            float* __restrict__ counts) {
    const int GROUPS = POOL_BLOCKS * 256 / 16;           // 640 node strips
    const int PER = (NN + GROUPS - 1) / GROUPS;          // 63
    int tid = blockIdx.x * blockDim.x + threadIdx.x;
    int f = tid & 15;
    int grp = tid >> 4;
    int n0 = grp * PER;
    int n1 = n0 + PER < NN ? n0 + PER : NN;
    if (n0 >= NN) return;
    int gcur = batch[n0];
    float acc = 0.f, cnt = 0.f;
    for (int n = n0; n < n1; ++n) {
        int g = batch[n];
        if (g != gcur) {
            atomicAdd(&sums[gcur * 16 + f], acc);
            if (f == 0) atomicAdd(&counts[gcur], cnt);
            acc = 0.f; cnt = 0.f; gcur = g;
        }
        acc += h[(size_t)n * 16 + f];
        cnt += 1.f;
    }
    atomicAdd(&sums[gcur * 16 + f], acc);
    if (f == 0) atomicAdd(&counts[gcur], cnt);
}

// ================= final FC =================
__global__ void fc_kernel(const float* __restrict__ sums,
                          const float* __restrict__ counts,
                          const float* __restrict__ Wfc,
                          const float* __restrict__ bfc,
                          float* __restrict__ out) {
    int g = threadIdx.x;
    if (g >= NG) return;
    float c = fmaxf(counts[g], 1.0f);
    float acc = bfc[0];
#pragma unroll
    for (int f = 0; f < 16; ++f) acc += (sums[g * 16 + f] / c) * Wfc[f];
    out[g] = acc;
}

extern "C" void kernel_launch(void* const* d_in, const int* in_sizes, int n_in,
                              void* d_out, int out_size, void* d_ws, size_t ws_size,
                              hipStream_t stream) {
    const float* x       = (const float*)d_in[0];
    const int*   ei      = (const int*)d_in[1];
    const int*   batch   = (const int*)d_in[2];
    const float* W1_rel  = (const float*)d_in[3];
    const float* b1      = (const float*)d_in[4];
    const float* W1_root = (const float*)d_in[5];
    const float* W2_rel  = (const float*)d_in[6];
    const float* b2      = (const float*)d_in[7];
    const float* W2_root = (const float*)d_in[8];
    const float* W3_rel  = (const float*)d_in[9];
    const float* b3      = (const float*)d_in[10];
    const float* W3_root = (const float*)d_in[11];
    const float* W4_rel  = (const float*)d_in[12];
    const float* b4      = (const float*)d_in[13];
    const float* W4_root = (const float*)d_in[14];
    const float* Wfc     = (const float*)d_in[15];
    const float* bfc     = (const float*)d_in[16];
    float* out = (float*)d_out;

    const int* src = ei;        // edge_index[0]
    const int* dst = ei + NE;   // edge_index[1]

    // workspace layout
    float* bufH   = (float*)d_ws;                  // N x 128
    float* bufY   = bufH + (size_t)NN * 128;       // N x 64
    float* bufZ   = bufY + (size_t)NN * 64;        // N x 64
    int*   deg    = (int*)(bufZ + (size_t)NN * 64);// N
    int*   rowptr = deg + NN;                      // N+1
    int*   cursor = rowptr + NN + 1;               // N
    int*   col    = cursor + NN;                   // E
    float* sums   = (float*)(col + NE);            // G x 16
    float* counts = sums + NG * 16;                // G

    // ---- build CSR (dst-sorted reverse adjacency), once per launch ----
    hipMemsetAsync(deg, 0, NN * sizeof(int), stream);
    hist_kernel<<<(NE + 255) / 256, 256, 0, stream>>>(dst, deg);
    scan_kernel<<<1, 1024, 0, stream>>>(deg, rowptr, cursor);
    fill_kernel<<<(NE + 255) / 256, 256, 0, stream>>>(src, dst, cursor, col);

    // ---- Layer 1: aggregate-first (din=32 < dout=128) ----
    gatherz_kernel<8, false, false><<<(NN * 8 + 255) / 256, 256, 0, stream>>>(
        (const float4*)x, nullptr, rowptr, col, (float4*)bufY, NN);
    conv1_kernel<32, 128><<<(NN + 31) / 32, 256, 0, stream>>>(
        (const float4*)bufY, (const float4*)x,
        (const float4*)W1_rel, (const float4*)W1_root, (const float4*)b1,
        (float4*)bufH, NN);

    // ---- Layer 2: transform-first (128 -> 64) ----
    mmyz_kernel<128, 64><<<(NN + 63) / 64, 256, 0, stream>>>(
        (const float4*)bufH, (const float4*)W2_rel, (const float4*)W2_root,
        (const float4*)b2, (float4*)bufY, (float4*)bufZ, NN);
    gatherz_kernel<16, true, true><<<(NN * 16 + 255) / 256, 256, 0, stream>>>(
        (const float4*)bufY, (const float4*)bufZ, rowptr, col, (float4*)bufH, NN);

    // ---- Layer 3: transform-first (64 -> 32) ----
    mmyz_kernel<64, 32><<<(NN + 127) / 128, 256, 0, stream>>>(
        (const float4*)bufH, (const float4*)W3_rel, (const float4*)W3_root,
        (const float4*)b3, (float4*)bufY, (float4*)bufZ, NN);
    gatherz_kernel<8, true, true><<<(NN * 8 + 255) / 256, 256, 0, stream>>>(
        (const float4*)bufY, (const float4*)bufZ, rowptr, col, (float4*)bufH, NN);

    // ---- Layer 4: transform-first (32 -> 16), no ReLU ----
    mmyz_kernel<32, 16><<<(NN + 255) / 256, 256, 0, stream>>>(
        (const float4*)bufH, (const float4*)W4_rel, (const float4*)W4_root,
        (const float4*)b4, (float4*)bufY, (float4*)bufZ, NN);
    gatherz_kernel<4, false, true><<<(NN * 4 + 255) / 256, 256, 0, stream>>>(
        (const float4*)bufY, (const float4*)bufZ, rowptr, col, (float4*)bufH, NN);

    // ---- Global mean pool + FC ----
    hipMemsetAsync(sums, 0, (size_t)(NG * 16 + NG) * sizeof(float), stream);
    pool_kernel<<<POOL_BLOCKS, 256, 0, stream>>>(bufH, batch, sums, counts);
    fc_kernel<<<1, 64, 0, stream>>>(sums, counts, Wfc, bfc, out);
}

// Round 5
// 303.192 us; speedup vs baseline: 6.0026x; 1.3733x over previous
//
#include <hip/hip_runtime.h>

#define NN 40000
#define NE 640000
#define NG 64

__device__ __forceinline__ float fcomp(const float4& v, int t) {
    return t == 0 ? v.x : t == 1 ? v.y : t == 2 ? v.z : v.w;
}

// ================= CSR build =================
__global__ void hist_kernel(const int* __restrict__ dst, int* __restrict__ deg) {
    int e = blockIdx.x * blockDim.x + threadIdx.x;
    if (e < NE) atomicAdd(&deg[dst[e]], 1);
}

// single-block exclusive scan over deg[NN] -> rowptr[NN+1], cursor[NN]
__global__ void scan_kernel(const int* __restrict__ deg,
                            int* __restrict__ rowptr,
                            int* __restrict__ cursor) {
    __shared__ int wsum[16];
    __shared__ int wpre[16];
    __shared__ int s_carry;
    __shared__ int s_total;
    int lane = threadIdx.x & 63;
    int wid = threadIdx.x >> 6;
    if (threadIdx.x == 0) s_carry = 0;
    __syncthreads();
    for (int base = 0; base < NN; base += 1024) {
        int i = base + threadIdx.x;
        int v = (i < NN) ? deg[i] : 0;
        int incl = v;
#pragma unroll
        for (int off = 1; off < 64; off <<= 1) {
            int t = __shfl_up(incl, off, 64);
            if (lane >= off) incl += t;
        }
        if (lane == 63) wsum[wid] = incl;
        __syncthreads();
        if (wid == 0 && lane < 16) {
            int wv = wsum[lane];
            int winc = wv;
#pragma unroll
            for (int off = 1; off < 16; off <<= 1) {
                int t = __shfl_up(winc, off, 64);
                if (lane >= off) winc += t;
            }
            wpre[lane] = winc - wv;
            if (lane == 15) s_total = winc;
        }
        __syncthreads();
        int carry = s_carry;
        int excl = carry + wpre[wid] + (incl - v);
        if (i < NN) { rowptr[i] = excl; cursor[i] = excl; }
        __syncthreads();
        if (threadIdx.x == 0) s_carry = carry + s_total;
        __syncthreads();
    }
    if (threadIdx.x == 0) rowptr[NN] = s_carry;
}

__global__ void fill_kernel(const int* __restrict__ src, const int* __restrict__ dst,
                            int* __restrict__ cursor, int* __restrict__ col) {
    int e = blockIdx.x * blockDim.x + threadIdx.x;
    if (e < NE) {
        int pos = atomicAdd(&cursor[dst[e]], 1);
        col[pos] = src[e];
    }
}

// ===== pure gather: out = act(z + sum_{j->i} y_j), D = 4*D4, 4-way unrolled =====
template<int D4, bool RELU, bool HAS_Z>
__global__ __launch_bounds__(256) void gatherz_kernel(
        const float4* __restrict__ y,
        const float4* __restrict__ z,
        const int* __restrict__ rowptr,
        const int* __restrict__ col,
        float4* __restrict__ out, int n) {
    int idx = blockIdx.x * blockDim.x + threadIdx.x;
    int node = idx / D4, c = idx % D4;
    if (node >= n) return;
    int beg = rowptr[node], end = rowptr[node + 1];
    float4 a;
    if (HAS_Z) a = z[(size_t)node * D4 + c];
    else { a.x = 0.f; a.y = 0.f; a.z = 0.f; a.w = 0.f; }
    int e = beg;
    for (; e + 4 <= end; e += 4) {
        int c0 = col[e], c1 = col[e + 1], c2 = col[e + 2], c3 = col[e + 3];
        float4 v0 = y[(size_t)c0 * D4 + c];
        float4 v1 = y[(size_t)c1 * D4 + c];
        float4 v2 = y[(size_t)c2 * D4 + c];
        float4 v3 = y[(size_t)c3 * D4 + c];
        a.x += (v0.x + v1.x) + (v2.x + v3.x);
        a.y += (v0.y + v1.y) + (v2.y + v3.y);
        a.z += (v0.z + v1.z) + (v2.z + v3.z);
        a.w += (v0.w + v1.w) + (v2.w + v3.w);
    }
    for (; e < end; ++e) {
        float4 v = y[(size_t)col[e] * D4 + c];
        a.x += v.x; a.y += v.y; a.z += v.z; a.w += v.w;
    }
    if (RELU) {
        a.x = fmaxf(a.x, 0.f); a.y = fmaxf(a.y, 0.f);
        a.z = fmaxf(a.z, 0.f); a.w = fmaxf(a.w, 0.f);
    }
    out[(size_t)node * D4 + c] = a;
}

// ====== layer-1 conv, register-blocked: out = relu(agg@Wrel + x@Wroot + b) ======
// thread = 2 nodes x 8 outputs; weights in LDS; unroll capped to avoid spill.
template<int K, int DOUT>   // 32, 128
__global__ __launch_bounds__(256, 4) void conv1_kernel(
        const float4* __restrict__ agg,   // N x K/4
        const float4* __restrict__ x,     // N x K/4
        const float4* __restrict__ Wrel,  // K x DOUT/4
        const float4* __restrict__ Wroot, // K x DOUT/4
        const float4* __restrict__ bias,  // DOUT/4
        float4* __restrict__ out, int n) {
    constexpr int W4 = DOUT / 4;          // float4s per weight row (32)
    constexpr int JG = DOUT / 8;          // 16 output-pair groups
    constexpr int MG = 256 / JG;          // 16 node-pair groups
    constexpr int NPB = MG * 2;           // 32 nodes per block
    __shared__ float4 sR[K * W4];         // 16 KB
    __shared__ float4 sT[K * W4];         // 16 KB
    for (int i = threadIdx.x; i < K * W4; i += 256) { sR[i] = Wrel[i]; sT[i] = Wroot[i]; }
    __syncthreads();
    int jg = threadIdx.x % JG;            // owns float4 columns 2*jg, 2*jg+1
    int mg = threadIdx.x / JG;
    int n0 = blockIdx.x * NPB + mg * 2;
    bool ok0 = n0 < n, ok1 = (n0 + 1) < n;
    int m0 = ok0 ? n0 : 0, m1 = ok1 ? (n0 + 1) : 0;
    float4 bb0 = bias[2 * jg], bb1 = bias[2 * jg + 1];
    float4 acc00 = bb0, acc01 = bb1;      // node0: out cols 2jg, 2jg+1
    float4 acc10 = bb0, acc11 = bb1;      // node1
#pragma unroll 2
    for (int kc = 0; kc < K / 4; ++kc) {
        float4 a0 = agg[(size_t)m0 * (K / 4) + kc];
        float4 x0 = x[(size_t)m0 * (K / 4) + kc];
        float4 a1 = agg[(size_t)m1 * (K / 4) + kc];
        float4 x1 = x[(size_t)m1 * (K / 4) + kc];
#pragma unroll
        for (int t = 0; t < 4; ++t) {
            int k = kc * 4 + t;
            float4 wr0 = sR[k * W4 + 2 * jg], wr1 = sR[k * W4 + 2 * jg + 1];
            float4 wt0 = sT[k * W4 + 2 * jg], wt1 = sT[k * W4 + 2 * jg + 1];
            float av0 = fcomp(a0, t), xv0 = fcomp(x0, t);
            float av1 = fcomp(a1, t), xv1 = fcomp(x1, t);
            acc00.x += av0 * wr0.x + xv0 * wt0.x;
            acc00.y += av0 * wr0.y + xv0 * wt0.y;
            acc00.z += av0 * wr0.z + xv0 * wt0.z;
            acc00.w += av0 * wr0.w + xv0 * wt0.w;
            acc01.x += av0 * wr1.x + xv0 * wt1.x;
            acc01.y += av0 * wr1.y + xv0 * wt1.y;
            acc01.z += av0 * wr1.z + xv0 * wt1.z;
            acc01.w += av0 * wr1.w + xv0 * wt1.w;
            acc10.x += av1 * wr0.x + xv1 * wt0.x;
            acc10.y += av1 * wr0.y + xv1 * wt0.y;
            acc10.z += av1 * wr0.z + xv1 * wt0.z;
            acc10.w += av1 * wr0.w + xv1 * wt0.w;
            acc11.x += av1 * wr1.x + xv1 * wt1.x;
            acc11.y += av1 * wr1.y + xv1 * wt1.y;
            acc11.z += av1 * wr1.z + xv1 * wt1.z;
            acc11.w += av1 * wr1.w + xv1 * wt1.w;
        }
    }
    if (ok0) {
        float4 r0, r1;
        r0.x = fmaxf(acc00.x, 0.f); r0.y = fmaxf(acc00.y, 0.f);
        r0.z = fmaxf(acc00.z, 0.f); r0.w = fmaxf(acc00.w, 0.f);
        r1.x = fmaxf(acc01.x, 0.f); r1.y = fmaxf(acc01.y, 0.f);
        r1.z = fmaxf(acc01.z, 0.f); r1.w = fmaxf(acc01.w, 0.f);
        out[(size_t)m0 * W4 + 2 * jg] = r0;
        out[(size_t)m0 * W4 + 2 * jg + 1] = r1;
    }
    if (ok1) {
        float4 r0, r1;
        r0.x = fmaxf(acc10.x, 0.f); r0.y = fmaxf(acc10.y, 0.f);
        r0.z = fmaxf(acc10.z, 0.f); r0.w = fmaxf(acc10.w, 0.f);
        r1.x = fmaxf(acc11.x, 0.f); r1.y = fmaxf(acc11.y, 0.f);
        r1.z = fmaxf(acc11.z, 0.f); r1.w = fmaxf(acc11.w, 0.f);
        out[(size_t)m1 * W4 + 2 * jg] = r0;
        out[(size_t)m1 * W4 + 2 * jg + 1] = r1;
    }
}

// ====== fused transform: y = h@Wrel, z = h@Wroot + b, register-blocked ======
// thread = 4 nodes x 4 outputs; k-slab (32) staged weights in LDS; unroll capped.
template<int K, int DOUT>
__global__ __launch_bounds__(256, 4) void mmyz_kernel(
        const float4* __restrict__ h,     // N x K/4
        const float4* __restrict__ Wrel,  // K x DOUT/4
        const float4* __restrict__ Wroot, // K x DOUT/4
        const float4* __restrict__ bias,  // DOUT/4
        float4* __restrict__ y,
        float4* __restrict__ z, int n) {
    constexpr int JL = DOUT / 4, MG = 256 / JL, NPB = MG * 4;
    constexpr int SLAB = 32, NS = K / SLAB;
    __shared__ float4 sR[SLAB * JL];
    __shared__ float4 sT[SLAB * JL];
    int jl = threadIdx.x % JL;
    int mg = threadIdx.x / JL;
    int node0 = blockIdx.x * NPB + mg * 4;
    int nm[4]; bool ok[4];
#pragma unroll
    for (int m = 0; m < 4; ++m) {
        int nd = node0 + m; ok[m] = nd < n; nm[m] = ok[m] ? nd : 0;
    }
    float4 bb = bias[jl];
    float4 ay[4], az[4];
#pragma unroll
    for (int m = 0; m < 4; ++m) {
        ay[m].x = 0.f; ay[m].y = 0.f; ay[m].z = 0.f; ay[m].w = 0.f;
        az[m] = bb;
    }
    for (int s = 0; s < NS; ++s) {
        __syncthreads();
        for (int i = threadIdx.x; i < SLAB * JL; i += 256) {
            sR[i] = Wrel[s * SLAB * JL + i];
            sT[i] = Wroot[s * SLAB * JL + i];
        }
        __syncthreads();
#pragma unroll 2
        for (int kc = 0; kc < SLAB / 4; ++kc) {
            float4 h4[4];
#pragma unroll
            for (int m = 0; m < 4; ++m)
                h4[m] = h[(size_t)nm[m] * (K / 4) + s * (SLAB / 4) + kc];
#pragma unroll
            for (int t = 0; t < 4; ++t) {
                float4 wr = sR[(kc * 4 + t) * JL + jl];
                float4 wt = sT[(kc * 4 + t) * JL + jl];
#pragma unroll
                for (int m = 0; m < 4; ++m) {
                    float hv = fcomp(h4[m], t);
                    ay[m].x += hv * wr.x; ay[m].y += hv * wr.y;
                    ay[m].z += hv * wr.z; ay[m].w += hv * wr.w;
                    az[m].x += hv * wt.x; az[m].y += hv * wt.y;
                    az[m].z += hv * wt.z; az[m].w += hv * wt.w;
                }
            }
        }
    }
#pragma unroll
    for (int m = 0; m < 4; ++m) {
        if (!ok[m]) continue;
        y[(size_t)nm[m] * JL + jl] = ay[m];
        z[(size_t)nm[m] * JL + jl] = az[m];
    }
}

// ======== mean-pool: run-based segmented reduction (batch is SORTED) ========
#define POOL_BLOCKS 40
__global__ void pool_kernel(const float* __restrict__ h,
                            const int* __restrict__ batch,
                            float* __restrict__ sums,
                            float* __restrict__ counts) {
    const int GROUPS = POOL_BLOCKS * 256 / 16;           // 640 node strips
    const int PER = (NN + GROUPS - 1) / GROUPS;          // 63
    int tid = blockIdx.x * blockDim.x + threadIdx.x;
    int f = tid & 15;
    int grp = tid >> 4;
    int n0 = grp * PER;
    int n1 = n0 + PER < NN ? n0 + PER : NN;
    if (n0 >= NN) return;
    int gcur = batch[n0];
    float acc = 0.f, cnt = 0.f;
    for (int n = n0; n < n1; ++n) {
        int g = batch[n];
        if (g != gcur) {
            atomicAdd(&sums[gcur * 16 + f], acc);
            if (f == 0) atomicAdd(&counts[gcur], cnt);
            acc = 0.f; cnt = 0.f; gcur = g;
        }
        acc += h[(size_t)n * 16 + f];
        cnt += 1.f;
    }
    atomicAdd(&sums[gcur * 16 + f], acc);
    if (f == 0) atomicAdd(&counts[gcur], cnt);
}

// ================= final FC =================
__global__ void fc_kernel(const float* __restrict__ sums,
                          const float* __restrict__ counts,
                          const float* __restrict__ Wfc,
                          const float* __restrict__ bfc,
                          float* __restrict__ out) {
    int g = threadIdx.x;
    if (g >= NG) return;
    float c = fmaxf(counts[g], 1.0f);
    float acc = bfc[0];
#pragma unroll
    for (int f = 0; f < 16; ++f) acc += (sums[g * 16 + f] / c) * Wfc[f];
    out[g] = acc;
}

extern "C" void kernel_launch(void* const* d_in, const int* in_sizes, int n_in,
                              void* d_out, int out_size, void* d_ws, size_t ws_size,
                              hipStream_t stream) {
    const float* x       = (const float*)d_in[0];
    const int*   ei      = (const int*)d_in[1];
    const int*   batch   = (const int*)d_in[2];
    const float* W1_rel  = (const float*)d_in[3];
    const float* b1      = (const float*)d_in[4];
    const float* W1_root = (const float*)d_in[5];
    const float* W2_rel  = (const float*)d_in[6];
    const float* b2      = (const float*)d_in[7];
    const float* W2_root = (const float*)d_in[8];
    const float* W3_rel  = (const float*)d_in[9];
    const float* b3      = (const float*)d_in[10];
    const float* W3_root = (const float*)d_in[11];
    const float* W4_rel  = (const float*)d_in[12];
    const float* b4      = (const float*)d_in[13];
    const float* W4_root = (const float*)d_in[14];
    const float* Wfc     = (const float*)d_in[15];
    const float* bfc     = (const float*)d_in[16];
    float* out = (float*)d_out;

    const int* src = ei;        // edge_index[0]
    const int* dst = ei + NE;   // edge_index[1]

    // workspace layout
    float* bufH   = (float*)d_ws;                  // N x 128
    float* bufY   = bufH + (size_t)NN * 128;       // N x 64
    float* bufZ   = bufY + (size_t)NN * 64;        // N x 64
    int*   deg    = (int*)(bufZ + (size_t)NN * 64);// N
    int*   rowptr = deg + NN;                      // N+1
    int*   cursor = rowptr + NN + 1;               // N
    int*   col    = cursor + NN;                   // E
    float* sums   = (float*)(col + NE);            // G x 16
    float* counts = sums + NG * 16;                // G

    // ---- build CSR (dst-sorted reverse adjacency), once per launch ----
    hipMemsetAsync(deg, 0, NN * sizeof(int), stream);
    hist_kernel<<<(NE + 255) / 256, 256, 0, stream>>>(dst, deg);
    scan_kernel<<<1, 1024, 0, stream>>>(deg, rowptr, cursor);
    fill_kernel<<<(NE + 255) / 256, 256, 0, stream>>>(src, dst, cursor, col);

    // ---- Layer 1: aggregate-first (din=32 < dout=128) ----
    gatherz_kernel<8, false, false><<<(NN * 8 + 255) / 256, 256, 0, stream>>>(
        (const float4*)x, nullptr, rowptr, col, (float4*)bufY, NN);
    conv1_kernel<32, 128><<<(NN + 31) / 32, 256, 0, stream>>>(
        (const float4*)bufY, (const float4*)x,
        (const float4*)W1_rel, (const float4*)W1_root, (const float4*)b1,
        (float4*)bufH, NN);

    // ---- Layer 2: transform-first (128 -> 64) ----
    mmyz_kernel<128, 64><<<(NN + 63) / 64, 256, 0, stream>>>(
        (const float4*)bufH, (const float4*)W2_rel, (const float4*)W2_root,
        (const float4*)b2, (float4*)bufY, (float4*)bufZ, NN);
    gatherz_kernel<16, true, true><<<(NN * 16 + 255) / 256, 256, 0, stream>>>(
        (const float4*)bufY, (const float4*)bufZ, rowptr, col, (float4*)bufH, NN);

    // ---- Layer 3: transform-first (64 -> 32) ----
    mmyz_kernel<64, 32><<<(NN + 127) / 128, 256, 0, stream>>>(
        (const float4*)bufH, (const float4*)W3_rel, (const float4*)W3_root,
        (const float4*)b3, (float4*)bufY, (float4*)bufZ, NN);
    gatherz_kernel<8, true, true><<<(NN * 8 + 255) / 256, 256, 0, stream>>>(
        (const float4*)bufY, (const float4*)bufZ, rowptr, col, (float4*)bufH, NN);

    // ---- Layer 4: transform-first (32 -> 16), no ReLU ----
    mmyz_kernel<32, 16><<<(NN + 255) / 256, 256, 0, stream>>>(
        (const float4*)bufH, (const float4*)W4_rel, (const float4*)W4_root,
        (const float4*)b4, (float4*)bufY, (float4*)bufZ, NN);
    gatherz_kernel<4, false, true><<<(NN * 4 + 255) / 256, 256, 0, stream>>>(
        (const float4*)bufY, (const float4*)bufZ, rowptr, col, (float4*)bufH, NN);

    // ---- Global mean pool + FC ----
    hipMemsetAsync(sums, 0, (size_t)(NG * 16 + NG) * sizeof(float), stream);
    pool_kernel<<<POOL_BLOCKS, 256, 0, stream>>>(bufH, batch, sums, counts);
    fc_kernel<<<1, 64, 0, stream>>>(sums, counts, Wfc, bfc, out);
}

// Round 6
// 292.014 us; speedup vs baseline: 6.2323x; 1.0383x over previous
//
#include <hip/hip_runtime.h>

#define NN 40000
#define NE 640000
#define NG 64

__device__ __forceinline__ float fcomp(const float4& v, int t) {
    return t == 0 ? v.x : t == 1 ? v.y : t == 2 ? v.z : v.w;
}

// ================= CSR build =================
__global__ void hist_kernel(const int* __restrict__ dst, int* __restrict__ deg) {
    int e = blockIdx.x * blockDim.x + threadIdx.x;
    if (e < NE) atomicAdd(&deg[dst[e]], 1);
}

// single-pass scan: 1024 threads x 40-elem serial strips + hierarchical total scan
__global__ __launch_bounds__(1024) void scan_kernel(const int* __restrict__ deg,
                                                    int* __restrict__ rowptr,
                                                    int* __restrict__ cursor) {
    constexpr int PT = 40;                 // 1024*40 = 40960 >= NN
    __shared__ int wsum[16];
    int t = threadIdx.x;
    int lane = t & 63, wid = t >> 6;
    int base = t * PT;
    int loc[PT];
    int sum = 0;
#pragma unroll
    for (int i = 0; i < PT; ++i) {
        int idx = base + i;
        int v = (idx < NN) ? deg[idx] : 0;
        loc[i] = sum;                      // thread-local exclusive
        sum += v;
    }
    int incl = sum;
#pragma unroll
    for (int off = 1; off < 64; off <<= 1) {
        int u = __shfl_up(incl, off, 64);
        if (lane >= off) incl += u;
    }
    if (lane == 63) wsum[wid] = incl;
    __syncthreads();
    if (wid == 0 && lane < 16) {
        int wv = wsum[lane];
        int winc = wv;
#pragma unroll
        for (int off = 1; off < 16; off <<= 1) {
            int u = __shfl_up(winc, off, 64);
            if (lane >= off) winc += u;
        }
        wsum[lane] = winc - wv;            // exclusive wave offset
    }
    __syncthreads();
    int offbase = wsum[wid] + (incl - sum);
#pragma unroll
    for (int i = 0; i < PT; ++i) {
        int idx = base + i;
        if (idx < NN) { int e = offbase + loc[i]; rowptr[idx] = e; cursor[idx] = e; }
    }
    if (t == 1023) rowptr[NN] = offbase + sum;
}

__global__ void fill_kernel(const int* __restrict__ src, const int* __restrict__ dst,
                            int* __restrict__ cursor, int* __restrict__ col) {
    int e = blockIdx.x * blockDim.x + threadIdx.x;
    if (e < NE) {
        int pos = atomicAdd(&cursor[dst[e]], 1);
        col[pos] = src[e];
    }
}

// ===== pure gather: out = act(z + sum_{j->i} y_j), D = 4*D4, 4-way unrolled =====
template<int D4, bool RELU, bool HAS_Z>
__global__ __launch_bounds__(256) void gatherz_kernel(
        const float4* __restrict__ y,
        const float4* __restrict__ z,
        const int* __restrict__ rowptr,
        const int* __restrict__ col,
        float4* __restrict__ out, int n) {
    int idx = blockIdx.x * blockDim.x + threadIdx.x;
    int node = idx / D4, c = idx % D4;
    if (node >= n) return;
    int beg = rowptr[node], end = rowptr[node + 1];
    float4 a;
    if (HAS_Z) a = z[(size_t)node * D4 + c];
    else { a.x = 0.f; a.y = 0.f; a.z = 0.f; a.w = 0.f; }
    int e = beg;
    for (; e + 4 <= end; e += 4) {
        int c0 = col[e], c1 = col[e + 1], c2 = col[e + 2], c3 = col[e + 3];
        float4 v0 = y[(size_t)c0 * D4 + c];
        float4 v1 = y[(size_t)c1 * D4 + c];
        float4 v2 = y[(size_t)c2 * D4 + c];
        float4 v3 = y[(size_t)c3 * D4 + c];
        a.x += (v0.x + v1.x) + (v2.x + v3.x);
        a.y += (v0.y + v1.y) + (v2.y + v3.y);
        a.z += (v0.z + v1.z) + (v2.z + v3.z);
        a.w += (v0.w + v1.w) + (v2.w + v3.w);
    }
    for (; e < end; ++e) {
        float4 v = y[(size_t)col[e] * D4 + c];
        a.x += v.x; a.y += v.y; a.z += v.z; a.w += v.w;
    }
    if (RELU) {
        a.x = fmaxf(a.x, 0.f); a.y = fmaxf(a.y, 0.f);
        a.z = fmaxf(a.z, 0.f); a.w = fmaxf(a.w, 0.f);
    }
    out[(size_t)node * D4 + c] = a;
}

// ====== layer-1 conv, register-blocked: out = relu(agg@Wrel + x@Wroot + b) ======
// thread = 2 nodes x 8 outputs; weights in LDS; unroll capped to avoid spill.
template<int K, int DOUT>   // 32, 128
__global__ __launch_bounds__(256, 4) void conv1_kernel(
        const float4* __restrict__ agg,   // N x K/4
        const float4* __restrict__ x,     // N x K/4
        const float4* __restrict__ Wrel,  // K x DOUT/4
        const float4* __restrict__ Wroot, // K x DOUT/4
        const float4* __restrict__ bias,  // DOUT/4
        float4* __restrict__ out, int n) {
    constexpr int W4 = DOUT / 4;
    constexpr int JG = DOUT / 8;
    constexpr int MG = 256 / JG;
    constexpr int NPB = MG * 2;
    __shared__ float4 sR[K * W4];
    __shared__ float4 sT[K * W4];
    for (int i = threadIdx.x; i < K * W4; i += 256) { sR[i] = Wrel[i]; sT[i] = Wroot[i]; }
    __syncthreads();
    int jg = threadIdx.x % JG;
    int mg = threadIdx.x / JG;
    int n0 = blockIdx.x * NPB + mg * 2;
    bool ok0 = n0 < n, ok1 = (n0 + 1) < n;
    int m0 = ok0 ? n0 : 0, m1 = ok1 ? (n0 + 1) : 0;
    float4 bb0 = bias[2 * jg], bb1 = bias[2 * jg + 1];
    float4 acc00 = bb0, acc01 = bb1;
    float4 acc10 = bb0, acc11 = bb1;
#pragma unroll 2
    for (int kc = 0; kc < K / 4; ++kc) {
        float4 a0 = agg[(size_t)m0 * (K / 4) + kc];
        float4 x0 = x[(size_t)m0 * (K / 4) + kc];
        float4 a1 = agg[(size_t)m1 * (K / 4) + kc];
        float4 x1 = x[(size_t)m1 * (K / 4) + kc];
#pragma unroll
        for (int t = 0; t < 4; ++t) {
            int k = kc * 4 + t;
            float4 wr0 = sR[k * W4 + 2 * jg], wr1 = sR[k * W4 + 2 * jg + 1];
            float4 wt0 = sT[k * W4 + 2 * jg], wt1 = sT[k * W4 + 2 * jg + 1];
            float av0 = fcomp(a0, t), xv0 = fcomp(x0, t);
            float av1 = fcomp(a1, t), xv1 = fcomp(x1, t);
            acc00.x += av0 * wr0.x + xv0 * wt0.x;
            acc00.y += av0 * wr0.y + xv0 * wt0.y;
            acc00.z += av0 * wr0.z + xv0 * wt0.z;
            acc00.w += av0 * wr0.w + xv0 * wt0.w;
            acc01.x += av0 * wr1.x + xv0 * wt1.x;
            acc01.y += av0 * wr1.y + xv0 * wt1.y;
            acc01.z += av0 * wr1.z + xv0 * wt1.z;
            acc01.w += av0 * wr1.w + xv0 * wt1.w;
            acc10.x += av1 * wr0.x + xv1 * wt0.x;
            acc10.y += av1 * wr0.y + xv1 * wt0.y;
            acc10.z += av1 * wr0.z + xv1 * wt0.z;
            acc10.w += av1 * wr0.w + xv1 * wt0.w;
            acc11.x += av1 * wr1.x + xv1 * wt1.x;
            acc11.y += av1 * wr1.y + xv1 * wt1.y;
            acc11.z += av1 * wr1.z + xv1 * wt1.z;
            acc11.w += av1 * wr1.w + xv1 * wt1.w;
        }
    }
    if (ok0) {
        float4 r0, r1;
        r0.x = fmaxf(acc00.x, 0.f); r0.y = fmaxf(acc00.y, 0.f);
        r0.z = fmaxf(acc00.z, 0.f); r0.w = fmaxf(acc00.w, 0.f);
        r1.x = fmaxf(acc01.x, 0.f); r1.y = fmaxf(acc01.y, 0.f);
        r1.z = fmaxf(acc01.z, 0.f); r1.w = fmaxf(acc01.w, 0.f);
        out[(size_t)m0 * W4 + 2 * jg] = r0;
        out[(size_t)m0 * W4 + 2 * jg + 1] = r1;
    }
    if (ok1) {
        float4 r0, r1;
        r0.x = fmaxf(acc10.x, 0.f); r0.y = fmaxf(acc10.y, 0.f);
        r0.z = fmaxf(acc10.z, 0.f); r0.w = fmaxf(acc10.w, 0.f);
        r1.x = fmaxf(acc11.x, 0.f); r1.y = fmaxf(acc11.y, 0.f);
        r1.z = fmaxf(acc11.z, 0.f); r1.w = fmaxf(acc11.w, 0.f);
        out[(size_t)m1 * W4 + 2 * jg] = r0;
        out[(size_t)m1 * W4 + 2 * jg + 1] = r1;
    }
}

// ====== fused transform: y = h@Wrel, z = h@Wroot + b, register-blocked ======
// NPT nodes per thread (grid-scaling knob); whole W staged once when <=16KB.
template<int K, int DOUT, int NPT>
__global__ __launch_bounds__(256, 6) void mmyz_kernel(
        const float4* __restrict__ h,     // N x K/4
        const float4* __restrict__ Wrel,  // K x DOUT/4
        const float4* __restrict__ Wroot, // K x DOUT/4
        const float4* __restrict__ bias,  // DOUT/4
        float4* __restrict__ y,
        float4* __restrict__ z, int n) {
    constexpr int JL = DOUT / 4, MG = 256 / JL, NPB = MG * NPT;
    constexpr int SLAB = (K * JL * 2 * 16 <= 16384) ? K : 32;
    constexpr int NS = K / SLAB;
    __shared__ float4 sR[SLAB * JL];
    __shared__ float4 sT[SLAB * JL];
    int jl = threadIdx.x % JL;
    int mg = threadIdx.x / JL;
    int node0 = blockIdx.x * NPB + mg * NPT;
    int nm[NPT]; bool ok[NPT];
#pragma unroll
    for (int m = 0; m < NPT; ++m) {
        int nd = node0 + m; ok[m] = nd < n; nm[m] = ok[m] ? nd : 0;
    }
    float4 bb = bias[jl];
    float4 ay[NPT], az[NPT];
#pragma unroll
    for (int m = 0; m < NPT; ++m) {
        ay[m].x = 0.f; ay[m].y = 0.f; ay[m].z = 0.f; ay[m].w = 0.f;
        az[m] = bb;
    }
    for (int s = 0; s < NS; ++s) {
        if (NS > 1) __syncthreads();
        for (int i = threadIdx.x; i < SLAB * JL; i += 256) {
            sR[i] = Wrel[s * SLAB * JL + i];
            sT[i] = Wroot[s * SLAB * JL + i];
        }
        __syncthreads();
#pragma unroll 2
        for (int kc = 0; kc < SLAB / 4; ++kc) {
            float4 h4[NPT];
#pragma unroll
            for (int m = 0; m < NPT; ++m)
                h4[m] = h[(size_t)nm[m] * (K / 4) + s * (SLAB / 4) + kc];
#pragma unroll
            for (int t = 0; t < 4; ++t) {
                float4 wr = sR[(kc * 4 + t) * JL + jl];
                float4 wt = sT[(kc * 4 + t) * JL + jl];
#pragma unroll
                for (int m = 0; m < NPT; ++m) {
                    float hv = fcomp(h4[m], t);
                    ay[m].x += hv * wr.x; ay[m].y += hv * wr.y;
                    ay[m].z += hv * wr.z; ay[m].w += hv * wr.w;
                    az[m].x += hv * wt.x; az[m].y += hv * wt.y;
                    az[m].z += hv * wt.z; az[m].w += hv * wt.w;
                }
            }
        }
    }
#pragma unroll
    for (int m = 0; m < NPT; ++m) {
        if (!ok[m]) continue;
        y[(size_t)nm[m] * JL + jl] = ay[m];
        z[(size_t)nm[m] * JL + jl] = az[m];
    }
}

// ======== mean-pool: run-based segmented reduction (batch is SORTED) ========
#define POOL_BLOCKS 40
__global__ void pool_kernel(const float* __restrict__ h,
                            const int* __restrict__ batch,
                            float* __restrict__ sums,
                            float* __restrict__ counts) {
    const int GROUPS = POOL_BLOCKS * 256 / 16;           // 640 node strips
    const int PER = (NN + GROUPS - 1) / GROUPS;          // 63
    int tid = blockIdx.x * blockDim.x + threadIdx.x;
    int f = tid & 15;
    int grp = tid >> 4;
    int n0 = grp * PER;
    int n1 = n0 + PER < NN ? n0 + PER : NN;
    if (n0 >= NN) return;
    int gcur = batch[n0];
    float acc = 0.f, cnt = 0.f;
    for (int n = n0; n < n1; ++n) {
        int g = batch[n];
        if (g != gcur) {
            atomicAdd(&sums[gcur * 16 + f], acc);
            if (f == 0) atomicAdd(&counts[gcur], cnt);
            acc = 0.f; cnt = 0.f; gcur = g;
        }
        acc += h[(size_t)n * 16 + f];
        cnt += 1.f;
    }
    atomicAdd(&sums[gcur * 16 + f], acc);
    if (f == 0) atomicAdd(&counts[gcur], cnt);
}

// ================= final FC =================
__global__ void fc_kernel(const float* __restrict__ sums,
                          const float* __restrict__ counts,
                          const float* __restrict__ Wfc,
                          const float* __restrict__ bfc,
                          float* __restrict__ out) {
    int g = threadIdx.x;
    if (g >= NG) return;
    float c = fmaxf(counts[g], 1.0f);
    float acc = bfc[0];
#pragma unroll
    for (int f = 0; f < 16; ++f) acc += (sums[g * 16 + f] / c) * Wfc[f];
    out[g] = acc;
}

extern "C" void kernel_launch(void* const* d_in, const int* in_sizes, int n_in,
                              void* d_out, int out_size, void* d_ws, size_t ws_size,
                              hipStream_t stream) {
    const float* x       = (const float*)d_in[0];
    const int*   ei      = (const int*)d_in[1];
    const int*   batch   = (const int*)d_in[2];
    const float* W1_rel  = (const float*)d_in[3];
    const float* b1      = (const float*)d_in[4];
    const float* W1_root = (const float*)d_in[5];
    const float* W2_rel  = (const float*)d_in[6];
    const float* b2      = (const float*)d_in[7];
    const float* W2_root = (const float*)d_in[8];
    const float* W3_rel  = (const float*)d_in[9];
    const float* b3      = (const float*)d_in[10];
    const float* W3_root = (const float*)d_in[11];
    const float* W4_rel  = (const float*)d_in[12];
    const float* b4      = (const float*)d_in[13];
    const float* W4_root = (const float*)d_in[14];
    const float* Wfc     = (const float*)d_in[15];
    const float* bfc     = (const float*)d_in[16];
    float* out = (float*)d_out;

    const int* src = ei;        // edge_index[0]
    const int* dst = ei + NE;   // edge_index[1]

    // workspace layout
    float* bufH   = (float*)d_ws;                  // N x 128
    float* bufY   = bufH + (size_t)NN * 128;       // N x 64
    float* bufZ   = bufY + (size_t)NN * 64;        // N x 64
    int*   deg    = (int*)(bufZ + (size_t)NN * 64);// N
    int*   rowptr = deg + NN;                      // N+1
    int*   cursor = rowptr + NN + 1;               // N
    int*   col    = cursor + NN;                   // E
    float* sums   = (float*)(col + NE);            // G x 16
    float* counts = sums + NG * 16;                // G

    // ---- build CSR (dst-sorted reverse adjacency), once per launch ----
    hipMemsetAsync(deg, 0, NN * sizeof(int), stream);
    hist_kernel<<<(NE + 255) / 256, 256, 0, stream>>>(dst, deg);
    scan_kernel<<<1, 1024, 0, stream>>>(deg, rowptr, cursor);
    fill_kernel<<<(NE + 255) / 256, 256, 0, stream>>>(src, dst, cursor, col);

    // ---- Layer 1: aggregate-first (din=32 < dout=128) ----
    gatherz_kernel<8, false, false><<<(NN * 8 + 255) / 256, 256, 0, stream>>>(
        (const float4*)x, nullptr, rowptr, col, (float4*)bufY, NN);
    conv1_kernel<32, 128><<<(NN + 31) / 32, 256, 0, stream>>>(
        (const float4*)bufY, (const float4*)x,
        (const float4*)W1_rel, (const float4*)W1_root, (const float4*)b1,
        (float4*)bufH, NN);

    // ---- Layer 2: transform-first (128 -> 64) ----
    mmyz_kernel<128, 64, 2><<<(NN + 31) / 32, 256, 0, stream>>>(
        (const float4*)bufH, (const float4*)W2_rel, (const float4*)W2_root,
        (const float4*)b2, (float4*)bufY, (float4*)bufZ, NN);
    gatherz_kernel<16, true, true><<<(NN * 16 + 255) / 256, 256, 0, stream>>>(
        (const float4*)bufY, (const float4*)bufZ, rowptr, col, (float4*)bufH, NN);

    // ---- Layer 3: transform-first (64 -> 32) ----
    mmyz_kernel<64, 32, 1><<<(NN + 31) / 32, 256, 0, stream>>>(
        (const float4*)bufH, (const float4*)W3_rel, (const float4*)W3_root,
        (const float4*)b3, (float4*)bufY, (float4*)bufZ, NN);
    gatherz_kernel<8, true, true><<<(NN * 8 + 255) / 256, 256, 0, stream>>>(
        (const float4*)bufY, (const float4*)bufZ, rowptr, col, (float4*)bufH, NN);

    // ---- Layer 4: transform-first (32 -> 16), no ReLU ----
    mmyz_kernel<32, 16, 1><<<(NN + 63) / 64, 256, 0, stream>>>(
        (const float4*)bufH, (const float4*)W4_rel, (const float4*)W4_root,
        (const float4*)b4, (float4*)bufY, (float4*)bufZ, NN);
    gatherz_kernel<4, false, true><<<(NN * 4 + 255) / 256, 256, 0, stream>>>(
        (const float4*)bufY, (const float4*)bufZ, rowptr, col, (float4*)bufH, NN);

    // ---- Global mean pool + FC ----
    hipMemsetAsync(sums, 0, (size_t)(NG * 16 + NG) * sizeof(float), stream);
    pool_kernel<<<POOL_BLOCKS, 256, 0, stream>>>(bufH, batch, sums, counts);
    fc_kernel<<<1, 64, 0, stream>>>(sums, counts, Wfc, bfc, out);
}

// Round 7
// 234.675 us; speedup vs baseline: 7.7551x; 1.2443x over previous
//
#include <hip/hip_runtime.h>

#define NN 40000
#define NE 640000
#define NG 64
#define SCAN_NB ((NN + 255) / 256)   // 157 blocks

__device__ __forceinline__ float fcomp(const float4& v, int t) {
    return t == 0 ? v.x : t == 1 ? v.y : t == 2 ? v.z : v.w;
}

// ================= CSR build =================
__global__ void hist_kernel(const int* __restrict__ dst, int* __restrict__ deg) {
    int e = blockIdx.x * blockDim.x + threadIdx.x;
    if (e < NE) atomicAdd(&deg[dst[e]], 1);
}

// pass 1: per-block exclusive scan (256 elems) + block total
__global__ __launch_bounds__(256) void scan1_kernel(const int* __restrict__ deg,
                                                    int* __restrict__ rowptr,
                                                    int* __restrict__ bsum) {
    __shared__ int ws[4];
    __shared__ int wpre[4];
    int i = blockIdx.x * 256 + threadIdx.x;
    int lane = threadIdx.x & 63, wid = threadIdx.x >> 6;
    int v = (i < NN) ? deg[i] : 0;
    int incl = v;
#pragma unroll
    for (int off = 1; off < 64; off <<= 1) {
        int u = __shfl_up(incl, off, 64);
        if (lane >= off) incl += u;
    }
    if (lane == 63) ws[wid] = incl;
    __syncthreads();
    if (threadIdx.x == 0) {
        int s = 0;
#pragma unroll
        for (int w = 0; w < 4; ++w) { wpre[w] = s; s += ws[w]; }
        bsum[blockIdx.x] = s;
    }
    __syncthreads();
    if (i < NN) rowptr[i] = wpre[wid] + (incl - v);
}

// pass 2: single-block exclusive scan of the block sums (SCAN_NB <= 256)
__global__ __launch_bounds__(256) void scan2_kernel(int* __restrict__ bsum,
                                                    int* __restrict__ rowptr) {
    __shared__ int ws[4];
    __shared__ int wpre[4];
    int t = threadIdx.x;
    int lane = t & 63, wid = t >> 6;
    int v = (t < SCAN_NB) ? bsum[t] : 0;
    int incl = v;
#pragma unroll
    for (int off = 1; off < 64; off <<= 1) {
        int u = __shfl_up(incl, off, 64);
        if (lane >= off) incl += u;
    }
    if (lane == 63) ws[wid] = incl;
    __syncthreads();
    if (t == 0) {
        int s = 0;
#pragma unroll
        for (int w = 0; w < 4; ++w) { wpre[w] = s; s += ws[w]; }
        rowptr[NN] = s;   // grand total = E
    }
    __syncthreads();
    if (t < SCAN_NB) bsum[t] = wpre[wid] + (incl - v);
}

// pass 3: add block offsets, emit cursor
__global__ __launch_bounds__(256) void scan3_kernel(int* __restrict__ rowptr,
                                                    const int* __restrict__ bsum,
                                                    int* __restrict__ cursor) {
    int i = blockIdx.x * 256 + threadIdx.x;
    if (i < NN) {
        int e = rowptr[i] + bsum[blockIdx.x];
        rowptr[i] = e;
        cursor[i] = e;
    }
}

__global__ void fill_kernel(const int* __restrict__ src, const int* __restrict__ dst,
                            int* __restrict__ cursor, int* __restrict__ col) {
    int e = blockIdx.x * blockDim.x + threadIdx.x;
    if (e < NE) {
        int pos = atomicAdd(&cursor[dst[e]], 1);
        col[pos] = src[e];
    }
}

// ===== pure gather: out = act(z + sum_{j->i} y_j), D = 4*D4, 4-way unrolled =====
template<int D4, bool RELU, bool HAS_Z>
__global__ __launch_bounds__(256) void gatherz_kernel(
        const float4* __restrict__ y,
        const float4* __restrict__ z,
        const int* __restrict__ rowptr,
        const int* __restrict__ col,
        float4* __restrict__ out, int n) {
    int idx = blockIdx.x * blockDim.x + threadIdx.x;
    int node = idx / D4, c = idx % D4;
    if (node >= n) return;
    int beg = rowptr[node], end = rowptr[node + 1];
    float4 a;
    if (HAS_Z) a = z[(size_t)node * D4 + c];
    else { a.x = 0.f; a.y = 0.f; a.z = 0.f; a.w = 0.f; }
    int e = beg;
    for (; e + 4 <= end; e += 4) {
        int c0 = col[e], c1 = col[e + 1], c2 = col[e + 2], c3 = col[e + 3];
        float4 v0 = y[(size_t)c0 * D4 + c];
        float4 v1 = y[(size_t)c1 * D4 + c];
        float4 v2 = y[(size_t)c2 * D4 + c];
        float4 v3 = y[(size_t)c3 * D4 + c];
        a.x += (v0.x + v1.x) + (v2.x + v3.x);
        a.y += (v0.y + v1.y) + (v2.y + v3.y);
        a.z += (v0.z + v1.z) + (v2.z + v3.z);
        a.w += (v0.w + v1.w) + (v2.w + v3.w);
    }
    for (; e < end; ++e) {
        float4 v = y[(size_t)col[e] * D4 + c];
        a.x += v.x; a.y += v.y; a.z += v.z; a.w += v.w;
    }
    if (RELU) {
        a.x = fmaxf(a.x, 0.f); a.y = fmaxf(a.y, 0.f);
        a.z = fmaxf(a.z, 0.f); a.w = fmaxf(a.w, 0.f);
    }
    out[(size_t)node * D4 + c] = a;
}

// ====== layer-1 conv, register-blocked: out = relu(agg@Wrel + x@Wroot + b) ======
template<int K, int DOUT>   // 32, 128
__global__ __launch_bounds__(256, 4) void conv1_kernel(
        const float4* __restrict__ agg,   // N x K/4
        const float4* __restrict__ x,     // N x K/4
        const float4* __restrict__ Wrel,  // K x DOUT/4
        const float4* __restrict__ Wroot, // K x DOUT/4
        const float4* __restrict__ bias,  // DOUT/4
        float4* __restrict__ out, int n) {
    constexpr int W4 = DOUT / 4;
    constexpr int JG = DOUT / 8;
    constexpr int MG = 256 / JG;
    constexpr int NPB = MG * 2;
    __shared__ float4 sR[K * W4];
    __shared__ float4 sT[K * W4];
    for (int i = threadIdx.x; i < K * W4; i += 256) { sR[i] = Wrel[i]; sT[i] = Wroot[i]; }
    __syncthreads();
    int jg = threadIdx.x % JG;
    int mg = threadIdx.x / JG;
    int n0 = blockIdx.x * NPB + mg * 2;
    bool ok0 = n0 < n, ok1 = (n0 + 1) < n;
    int m0 = ok0 ? n0 : 0, m1 = ok1 ? (n0 + 1) : 0;
    float4 bb0 = bias[2 * jg], bb1 = bias[2 * jg + 1];
    float4 acc00 = bb0, acc01 = bb1;
    float4 acc10 = bb0, acc11 = bb1;
#pragma unroll 2
    for (int kc = 0; kc < K / 4; ++kc) {
        float4 a0 = agg[(size_t)m0 * (K / 4) + kc];
        float4 x0 = x[(size_t)m0 * (K / 4) + kc];
        float4 a1 = agg[(size_t)m1 * (K / 4) + kc];
        float4 x1 = x[(size_t)m1 * (K / 4) + kc];
#pragma unroll
        for (int t = 0; t < 4; ++t) {
            int k = kc * 4 + t;
            float4 wr0 = sR[k * W4 + 2 * jg], wr1 = sR[k * W4 + 2 * jg + 1];
            float4 wt0 = sT[k * W4 + 2 * jg], wt1 = sT[k * W4 + 2 * jg + 1];
            float av0 = fcomp(a0, t), xv0 = fcomp(x0, t);
            float av1 = fcomp(a1, t), xv1 = fcomp(x1, t);
            acc00.x += av0 * wr0.x + xv0 * wt0.x;
            acc00.y += av0 * wr0.y + xv0 * wt0.y;
            acc00.z += av0 * wr0.z + xv0 * wt0.z;
            acc00.w += av0 * wr0.w + xv0 * wt0.w;
            acc01.x += av0 * wr1.x + xv0 * wt1.x;
            acc01.y += av0 * wr1.y + xv0 * wt1.y;
            acc01.z += av0 * wr1.z + xv0 * wt1.z;
            acc01.w += av0 * wr1.w + xv0 * wt1.w;
            acc10.x += av1 * wr0.x + xv1 * wt0.x;
            acc10.y += av1 * wr0.y + xv1 * wt0.y;
            acc10.z += av1 * wr0.z + xv1 * wt0.z;
            acc10.w += av1 * wr0.w + xv1 * wt0.w;
            acc11.x += av1 * wr1.x + xv1 * wt1.x;
            acc11.y += av1 * wr1.y + xv1 * wt1.y;
            acc11.z += av1 * wr1.z + xv1 * wt1.z;
            acc11.w += av1 * wr1.w + xv1 * wt1.w;
        }
    }
    if (ok0) {
        float4 r0, r1;
        r0.x = fmaxf(acc00.x, 0.f); r0.y = fmaxf(acc00.y, 0.f);
        r0.z = fmaxf(acc00.z, 0.f); r0.w = fmaxf(acc00.w, 0.f);
        r1.x = fmaxf(acc01.x, 0.f); r1.y = fmaxf(acc01.y, 0.f);
        r1.z = fmaxf(acc01.z, 0.f); r1.w = fmaxf(acc01.w, 0.f);
        out[(size_t)m0 * W4 + 2 * jg] = r0;
        out[(size_t)m0 * W4 + 2 * jg + 1] = r1;
    }
    if (ok1) {
        float4 r0, r1;
        r0.x = fmaxf(acc10.x, 0.f); r0.y = fmaxf(acc10.y, 0.f);
        r0.z = fmaxf(acc10.z, 0.f); r0.w = fmaxf(acc10.w, 0.f);
        r1.x = fmaxf(acc11.x, 0.f); r1.y = fmaxf(acc11.y, 0.f);
        r1.z = fmaxf(acc11.z, 0.f); r1.w = fmaxf(acc11.w, 0.f);
        out[(size_t)m1 * W4 + 2 * jg] = r0;
        out[(size_t)m1 * W4 + 2 * jg + 1] = r1;
    }
}

// ====== fused transform: y = h@Wrel, z = h@Wroot + b, register-blocked ======
template<int K, int DOUT, int NPT>
__global__ __launch_bounds__(256, 6) void mmyz_kernel(
        const float4* __restrict__ h,     // N x K/4
        const float4* __restrict__ Wrel,  // K x DOUT/4
        const float4* __restrict__ Wroot, // K x DOUT/4
        const float4* __restrict__ bias,  // DOUT/4
        float4* __restrict__ y,
        float4* __restrict__ z, int n) {
    constexpr int JL = DOUT / 4, MG = 256 / JL, NPB = MG * NPT;
    constexpr int SLAB = (K * JL * 2 * 16 <= 16384) ? K : 32;
    constexpr int NS = K / SLAB;
    __shared__ float4 sR[SLAB * JL];
    __shared__ float4 sT[SLAB * JL];
    int jl = threadIdx.x % JL;
    int mg = threadIdx.x / JL;
    int node0 = blockIdx.x * NPB + mg * NPT;
    int nm[NPT]; bool ok[NPT];
#pragma unroll
    for (int m = 0; m < NPT; ++m) {
        int nd = node0 + m; ok[m] = nd < n; nm[m] = ok[m] ? nd : 0;
    }
    float4 bb = bias[jl];
    float4 ay[NPT], az[NPT];
#pragma unroll
    for (int m = 0; m < NPT; ++m) {
        ay[m].x = 0.f; ay[m].y = 0.f; ay[m].z = 0.f; ay[m].w = 0.f;
        az[m] = bb;
    }
    for (int s = 0; s < NS; ++s) {
        if (NS > 1) __syncthreads();
        for (int i = threadIdx.x; i < SLAB * JL; i += 256) {
            sR[i] = Wrel[s * SLAB * JL + i];
            sT[i] = Wroot[s * SLAB * JL + i];
        }
        __syncthreads();
#pragma unroll 2
        for (int kc = 0; kc < SLAB / 4; ++kc) {
            float4 h4[NPT];
#pragma unroll
            for (int m = 0; m < NPT; ++m)
                h4[m] = h[(size_t)nm[m] * (K / 4) + s * (SLAB / 4) + kc];
#pragma unroll
            for (int t = 0; t < 4; ++t) {
                float4 wr = sR[(kc * 4 + t) * JL + jl];
                float4 wt = sT[(kc * 4 + t) * JL + jl];
#pragma unroll
                for (int m = 0; m < NPT; ++m) {
                    float hv = fcomp(h4[m], t);
                    ay[m].x += hv * wr.x; ay[m].y += hv * wr.y;
                    ay[m].z += hv * wr.z; ay[m].w += hv * wr.w;
                    az[m].x += hv * wt.x; az[m].y += hv * wt.y;
                    az[m].z += hv * wt.z; az[m].w += hv * wt.w;
                }
            }
        }
    }
#pragma unroll
    for (int m = 0; m < NPT; ++m) {
        if (!ok[m]) continue;
        y[(size_t)nm[m] * JL + jl] = ay[m];
        z[(size_t)nm[m] * JL + jl] = az[m];
    }
}

// ======== mean-pool: run-based segmented reduction (batch is SORTED) ========
#define POOL_BLOCKS 40
__global__ void pool_kernel(const float* __restrict__ h,
                            const int* __restrict__ batch,
                            float* __restrict__ sums,
                            float* __restrict__ counts) {
    const int GROUPS = POOL_BLOCKS * 256 / 16;           // 640 node strips
    const int PER = (NN + GROUPS - 1) / GROUPS;          // 63
    int tid = blockIdx.x * blockDim.x + threadIdx.x;
    int f = tid & 15;
    int grp = tid >> 4;
    int n0 = grp * PER;
    int n1 = n0 + PER < NN ? n0 + PER : NN;
    if (n0 >= NN) return;
    int gcur = batch[n0];
    float acc = 0.f, cnt = 0.f;
    for (int n = n0; n < n1; ++n) {
        int g = batch[n];
        if (g != gcur) {
            atomicAdd(&sums[gcur * 16 + f], acc);
            if (f == 0) atomicAdd(&counts[gcur], cnt);
            acc = 0.f; cnt = 0.f; gcur = g;
        }
        acc += h[(size_t)n * 16 + f];
        cnt += 1.f;
    }
    atomicAdd(&sums[gcur * 16 + f], acc);
    if (f == 0) atomicAdd(&counts[gcur], cnt);
}

// ================= final FC =================
__global__ void fc_kernel(const float* __restrict__ sums,
                          const float* __restrict__ counts,
                          const float* __restrict__ Wfc,
                          const float* __restrict__ bfc,
                          float* __restrict__ out) {
    int g = threadIdx.x;
    if (g >= NG) return;
    float c = fmaxf(counts[g], 1.0f);
    float acc = bfc[0];
#pragma unroll
    for (int f = 0; f < 16; ++f) acc += (sums[g * 16 + f] / c) * Wfc[f];
    out[g] = acc;
}

extern "C" void kernel_launch(void* const* d_in, const int* in_sizes, int n_in,
                              void* d_out, int out_size, void* d_ws, size_t ws_size,
                              hipStream_t stream) {
    const float* x       = (const float*)d_in[0];
    const int*   ei      = (const int*)d_in[1];
    const int*   batch   = (const int*)d_in[2];
    const float* W1_rel  = (const float*)d_in[3];
    const float* b1      = (const float*)d_in[4];
    const float* W1_root = (const float*)d_in[5];
    const float* W2_rel  = (const float*)d_in[6];
    const float* b2      = (const float*)d_in[7];
    const float* W2_root = (const float*)d_in[8];
    const float* W3_rel  = (const float*)d_in[9];
    const float* b3      = (const float*)d_in[10];
    const float* W3_root = (const float*)d_in[11];
    const float* W4_rel  = (const float*)d_in[12];
    const float* b4      = (const float*)d_in[13];
    const float* W4_root = (const float*)d_in[14];
    const float* Wfc     = (const float*)d_in[15];
    const float* bfc     = (const float*)d_in[16];
    float* out = (float*)d_out;

    const int* src = ei;        // edge_index[0]
    const int* dst = ei + NE;   // edge_index[1]

    // workspace layout
    float* bufH   = (float*)d_ws;                  // N x 128
    float* bufY   = bufH + (size_t)NN * 128;       // N x 64
    float* bufZ   = bufY + (size_t)NN * 64;        // N x 64
    int*   deg    = (int*)(bufZ + (size_t)NN * 64);// N
    int*   rowptr = deg + NN;                      // N+1
    int*   cursor = rowptr + NN + 1;               // N
    int*   col    = cursor + NN;                   // E
    int*   bsum   = col + NE;                      // SCAN_NB
    float* sums   = (float*)(bsum + SCAN_NB);      // G x 16
    float* counts = sums + NG * 16;                // G

    // ---- build CSR (dst-sorted reverse adjacency), once per launch ----
    hipMemsetAsync(deg, 0, NN * sizeof(int), stream);
    hist_kernel<<<(NE + 255) / 256, 256, 0, stream>>>(dst, deg);
    scan1_kernel<<<SCAN_NB, 256, 0, stream>>>(deg, rowptr, bsum);
    scan2_kernel<<<1, 256, 0, stream>>>(bsum, rowptr);
    scan3_kernel<<<SCAN_NB, 256, 0, stream>>>(rowptr, bsum, cursor);
    fill_kernel<<<(NE + 255) / 256, 256, 0, stream>>>(src, dst, cursor, col);

    // ---- Layer 1: aggregate-first (din=32 < dout=128) ----
    gatherz_kernel<8, false, false><<<(NN * 8 + 255) / 256, 256, 0, stream>>>(
        (const float4*)x, nullptr, rowptr, col, (float4*)bufY, NN);
    conv1_kernel<32, 128><<<(NN + 31) / 32, 256, 0, stream>>>(
        (const float4*)bufY, (const float4*)x,
        (const float4*)W1_rel, (const float4*)W1_root, (const float4*)b1,
        (float4*)bufH, NN);

    // ---- Layer 2: transform-first (128 -> 64) ----
    mmyz_kernel<128, 64, 2><<<(NN + 31) / 32, 256, 0, stream>>>(
        (const float4*)bufH, (const float4*)W2_rel, (const float4*)W2_root,
        (const float4*)b2, (float4*)bufY, (float4*)bufZ, NN);
    gatherz_kernel<16, true, true><<<(NN * 16 + 255) / 256, 256, 0, stream>>>(
        (const float4*)bufY, (const float4*)bufZ, rowptr, col, (float4*)bufH, NN);

    // ---- Layer 3: transform-first (64 -> 32) ----
    mmyz_kernel<64, 32, 1><<<(NN + 31) / 32, 256, 0, stream>>>(
        (const float4*)bufH, (const float4*)W3_rel, (const float4*)W3_root,
        (const float4*)b3, (float4*)bufY, (float4*)bufZ, NN);
    gatherz_kernel<8, true, true><<<(NN * 8 + 255) / 256, 256, 0, stream>>>(
        (const float4*)bufY, (const float4*)bufZ, rowptr, col, (float4*)bufH, NN);

    // ---- Layer 4: transform-first (32 -> 16), no ReLU ----
    mmyz_kernel<32, 16, 1><<<(NN + 63) / 64, 256, 0, stream>>>(
        (const float4*)bufH, (const float4*)W4_rel, (const float4*)W4_root,
        (const float4*)b4, (float4*)bufY, (float4*)bufZ, NN);
    gatherz_kernel<4, false, true><<<(NN * 4 + 255) / 256, 256, 0, stream>>>(
        (const float4*)bufY, (const float4*)bufZ, rowptr, col, (float4*)bufH, NN);

    // ---- Global mean pool + FC ----
    hipMemsetAsync(sums, 0, (size_t)(NG * 16 + NG) * sizeof(float), stream);
    pool_kernel<<<POOL_BLOCKS, 256, 0, stream>>>(bufH, batch, sums, counts);
    fc_kernel<<<1, 64, 0, stream>>>(sums, counts, Wfc, bfc, out);
}